// Round 5
// baseline (638.482 us; speedup 1.0000x reference)
//
#include <hip/hip_runtime.h>
#include <math.h>

// VQ-AE forward, single fused kernel + software grid barriers (R5).
// R4 (128-row tiles, 2 blocks/CU) was latency-bound: 276us at 6% HBM / 3% MFMA /
// 23% occupancy. R5: 1024 blocks x 64 rows, LDS pool 39.2KB -> 4 blocks/CU
// (16 waves/CU), launch_bounds(256,4) caps VGPR at 128. All weights pre-converted
// to bf16 (B-layouts) in k_prep -> all B staging is coalesced uint4 copies.
// Structure: P1 enc1 (h1 in regs) -> gsync -> P2 BN1+enc2(split-bf16)+quant+dec1
// (h2 in regs) -> gsync -> P3 BN2+dec2 with direct (X_-X)^2 epilogue (X re-read
// L3-resident). No intermediate HBM arrays.
// z-path accuracy-critical: h1 fp32 in regs, z via split-bf16 MFMA (3 products),
// exact fp32 selected-distance. Post-topics path single bf16.
//
// ws: acc[1024] f32 | cbb[1024*32] bf16 | cn_g[1024] f32 | w1T bf16[128][512]
//     | w2dT bf16[512][128] | w1dTg bf16[128][32] | w2eh/w2el bf16[32][128]
// acc: [0..127] sum1, [128..255] sumsq1, [256..383] sum2, [384..511] sumsq2,
//      [512] min-dist sum, [513] sum((X_-X)^2), [520] barrier counter (int)

typedef __attribute__((ext_vector_type(8))) short bf8;
typedef __attribute__((ext_vector_type(4))) float f4a;

__device__ __forceinline__ unsigned short f2bf(float f) {
    unsigned u = __float_as_uint(f);
    u += 0x7fffu + ((u >> 16) & 1u);   // RNE
    return (unsigned short)(u >> 16);
}
__device__ __forceinline__ float bf2f(unsigned short h) {
    return __uint_as_float((unsigned)h << 16);
}
__device__ __forceinline__ unsigned pack2(float a, float b) {
    return (unsigned)f2bf(a) | ((unsigned)f2bf(b) << 16);
}

// Monotonic software grid barrier (validated in R4: passed, absmax 0).
// All blocks co-resident by construction. Data crossing the barrier is written
// ONLY via device-scope atomicAdd; post-barrier readers use agent-scope loads.
__device__ __forceinline__ void gsync(int* cnt, int goal) {
    __syncthreads();
    if (threadIdx.x == 0) {
        __threadfence();
        __hip_atomic_fetch_add(cnt, 1, __ATOMIC_RELEASE, __HIP_MEMORY_SCOPE_AGENT);
        while (__hip_atomic_load(cnt, __ATOMIC_ACQUIRE, __HIP_MEMORY_SCOPE_AGENT) < goal)
            __builtin_amdgcn_s_sleep(2);
    }
    __syncthreads();
}
__device__ __forceinline__ float aload(const float* p) {
    return __hip_atomic_load(p, __ATOMIC_RELAXED, __HIP_MEMORY_SCOPE_AGENT);
}

// ======== K0: zero acc + codebook->bf16+norms + weight pre-conversion ========
__global__ __launch_bounds__(256) void k_prep(const float* __restrict__ cb,
                                              const float* __restrict__ w1,
                                              const float* __restrict__ w2d,
                                              const float* __restrict__ w1d,
                                              const float* __restrict__ w2e,
                                              float* __restrict__ acc,
                                              unsigned short* __restrict__ cbb,
                                              float* __restrict__ cn_g,
                                              unsigned short* __restrict__ w1T,
                                              unsigned short* __restrict__ w2dT,
                                              unsigned short* __restrict__ w1dTg,
                                              unsigned short* __restrict__ w2eh,
                                              unsigned short* __restrict__ w2el) {
    const int b = blockIdx.x, t = threadIdx.x;
    if (b < 4) {                       // codebook -> bf16 + fp32 norms
        const int cw = (b << 8) + t;
        const float* p = cb + (size_t)cw * 32;
        unsigned out[16];
        float n = 0.f;
#pragma unroll
        for (int i = 0; i < 8; ++i) {
            float4 v = *(const float4*)(p + (i << 2));
            n = fmaf(v.x, v.x, n); n = fmaf(v.y, v.y, n);
            n = fmaf(v.z, v.z, n); n = fmaf(v.w, v.w, n);
            out[2 * i]     = pack2(v.x, v.y);
            out[2 * i + 1] = pack2(v.z, v.w);
        }
#pragma unroll
        for (int i = 0; i < 4; ++i)
            *(uint4*)(cbb + (size_t)cw * 32 + (i << 3)) =
                make_uint4(out[4 * i], out[4 * i + 1], out[4 * i + 2], out[4 * i + 3]);
        cn_g[cw] = n;
    } else if (b == 4) {               // zero accumulators + barrier
        for (int i = t; i < 1024; i += 256) acc[i] = 0.f;
    } else if (b < 21) {               // w1T[n][k] <- w1[k][n] (16 blocks x 8 rows)
        const int n0 = (b - 5) << 3;
        for (int rr = 0; rr < 8; ++rr) {
            const int n = n0 + rr;
            w1T[(size_t)n * 512 + t]       = f2bf(w1[(size_t)t * 128 + n]);
            w1T[(size_t)n * 512 + 256 + t] = f2bf(w1[(size_t)(256 + t) * 128 + n]);
        }
    } else if (b < 85) {               // w2dT[n][k] <- w2d[k][n] (64 blocks x 8 rows)
        const int n0 = (b - 21) << 3;
        if (t < 128)
            for (int rr = 0; rr < 8; ++rr) {
                const int n = n0 + rr;
                w2dT[(size_t)n * 128 + t] = f2bf(w2d[(size_t)t * 512 + n]);
            }
    } else if (b == 85) {              // w1dTg[n][k] <- w1d[k][n], [128][32]
        for (int i = 0; i < 16; ++i) {
            const int idx = (i << 8) + t;
            const int n = idx >> 5, k = idx & 31;
            w1dTg[idx] = f2bf(w1d[(size_t)k * 128 + n]);
        }
    } else {                           // b==86: w2e hi/lo split [32 n][128 k]
        for (int i = 0; i < 16; ++i) {
            const int idx = (i << 8) + t;
            const int n = idx >> 7, k = idx & 127;
            const float f = w2e[(size_t)k * 32 + n];
            unsigned short hi = f2bf(f);
            w2eh[idx] = hi;
            w2el[idx] = f2bf(f - bf2f(hi));
        }
    }
}

// ======== K1: fused pipeline (1024 x 256, 4 blocks/CU, 64 rows/block) ========
// LDS pool 39168 B:
//  [0,27648)  region0:
//    P1:  As[64][72] @0 | Bs(w1T chunk)[128][72] @9216
//    P2a: Ash @0 | Asl @9216 | B2h[32][72] @18432 | B2l @23040
//    P2b: cs[256][40] @0 | cn f32[256] @20480
//    P2c: W1dT[128][40] @0 | Qs[64][40] @10240 | sst2 f32[1024] @15360
//    P3:  Ad[64][136] @0 | Bsd[128][40] @17408
//  [27648,32768) zs bf16[64][40] | [32768,33792) scl/shf | [33792,34048) topicsL
//  [34048,35072) red f32[256] | [35072,39168) sred f32[1024]
__global__ __launch_bounds__(256, 4) void k_fused(
    const float* __restrict__ X,
    const float* __restrict__ b1,
    const float* __restrict__ g1,
    const float* __restrict__ be1,
    const float* __restrict__ b2e,
    const float* __restrict__ b1d,
    const float* __restrict__ g2,
    const float* __restrict__ be2,
    const float* __restrict__ b2d,
    const float* __restrict__ cb,
    const unsigned short* __restrict__ cbb,
    const float* __restrict__ cn_g,
    const unsigned short* __restrict__ w1T,
    const unsigned short* __restrict__ w2dT,
    const unsigned short* __restrict__ w1dTg,
    const unsigned short* __restrict__ w2eh,
    const unsigned short* __restrict__ w2el,
    float* __restrict__ acc_g)
{
    __shared__ __align__(16) char pool[39168];
    unsigned short* As   = (unsigned short*)pool;               // P1 A / P2a Ash
    unsigned short* Bs   = (unsigned short*)(pool + 9216);      // P1 B / P2a Asl
    unsigned short* B2h  = (unsigned short*)(pool + 18432);
    unsigned short* B2l  = (unsigned short*)(pool + 23040);
    unsigned short* cs   = (unsigned short*)pool;
    float*          cn   = (float*)(pool + 20480);
    unsigned short* W1dT = (unsigned short*)pool;
    unsigned short* Qs   = (unsigned short*)(pool + 10240);
    float*          sst2 = (float*)(pool + 15360);
    unsigned short* Ad   = (unsigned short*)pool;               // P3 [64][136]
    unsigned short* Bsd  = (unsigned short*)(pool + 17408);     // P3 [128][40]
    unsigned short* zs   = (unsigned short*)(pool + 27648);
    float* scl     = (float*)(pool + 32768);
    float* shf     = (float*)(pool + 33280);
    int*   topicsL = (int*)(pool + 33792);
    float* red     = (float*)(pool + 34048);
    float* sred    = (float*)(pool + 35072);

    const int t = threadIdx.x;
    const int w = t >> 6, lane = t & 63, quad = lane >> 4, lcol = lane & 15;
    const int row0 = blockIdx.x << 6;    // 64 rows/block
    int* bar = (int*)(acc_g + 520);

    // ================= P1: h1 = X@w1 (regs) + BN1 column stats =================
    f4a acc[8];
#pragma unroll
    for (int j = 0; j < 8; ++j) acc[j] = (f4a){0.f, 0.f, 0.f, 0.f};

    const int arb = t >> 4;               // A: 16 rows per step
    const int akq = (t & 15) << 2;        // A k-quad
    const int bnr = t >> 3, bu = t & 7;   // B: row / uint4-slot

    for (int c = 0; c < 8; ++c) {
        const int k0 = c << 6;
        __syncthreads();
#pragma unroll
        for (int i = 0; i < 4; ++i) {     // A: X tile -> bf16 [64][72]
            const int r = (i << 4) + arb;
            float4 v = *(const float4*)(X + (size_t)(row0 + r) * 512 + k0 + akq);
            *(uint2*)&As[r * 72 + akq] = make_uint2(pack2(v.x, v.y), pack2(v.z, v.w));
        }
#pragma unroll
        for (int i = 0; i < 4; ++i) {     // B: w1T chunk, coalesced uint4 copies
            const int n = (i << 5) + bnr;
            *(uint4*)&Bs[n * 72 + (bu << 3)] =
                *(const uint4*)(w1T + (size_t)n * 512 + k0 + (bu << 3));
        }
        __syncthreads();
#pragma unroll
        for (int ks = 0; ks < 2; ++ks) {
            const bf8 a0 = *(const bf8*)&As[(w * 16 + lcol) * 72 + (ks << 5) + (quad << 3)];
#pragma unroll
            for (int nt = 0; nt < 8; ++nt) {
                const bf8 bb = *(const bf8*)&Bs[(nt * 16 + lcol) * 72 + (ks << 5) + (quad << 3)];
                acc[nt] = __builtin_amdgcn_mfma_f32_16x16x32_bf16(a0, bb, acc[nt], 0, 0, 0);
            }
        }
    }
    // BN1 column stats (h1 never leaves registers)
#pragma unroll
    for (int nt = 0; nt < 8; ++nt) {
        const int gc = (nt << 4) + lcol;
        const float bias = b1[gc];
        float s = 0.f, ss = 0.f;
#pragma unroll
        for (int r = 0; r < 4; ++r) {
            float v = acc[nt][r] + bias;
            s += v;
            ss = fmaf(v, v, ss);
        }
        s += __shfl_xor(s, 16);  s += __shfl_xor(s, 32);
        ss += __shfl_xor(ss, 16); ss += __shfl_xor(ss, 32);
        if (quad == 0) { sred[w * 128 + gc] = s; sred[512 + w * 128 + gc] = ss; }
    }
    __syncthreads();
    if (t < 128) {
        atomicAdd(&acc_g[t], sred[t] + sred[128 + t] + sred[256 + t] + sred[384 + t]);
        atomicAdd(&acc_g[128 + t], sred[512 + t] + sred[640 + t] + sred[768 + t] + sred[896 + t]);
    }
    gsync(bar, 1024);

    // ================= P2: BN1 -> z (split-bf16) -> quant -> dec1 =================
    if (t < 128) {
        float mu = aload(&acc_g[t]) * (1.f / 65536.f);
        float var = fmaf(-mu, mu, aload(&acc_g[128 + t]) * (1.f / 65536.f));
        float s = g1[t] * rsqrtf(var + 1e-5f);
        scl[t] = s;
        shf[t] = fmaf(-mu, s, be1[t]);
    }
    __syncthreads();

    f4a zacc[2];
#pragma unroll
    for (int j = 0; j < 2; ++j) zacc[j] = (f4a){0.f, 0.f, 0.f, 0.f};

    // K=128 in two 64-wide chunks; A = relu(bn1(h1)) hi/lo from own regs
#pragma unroll
    for (int h = 0; h < 2; ++h) {
#pragma unroll
        for (int nt4 = 0; nt4 < 4; ++nt4) {
            const int nt = (h << 2) + nt4;
            const int gc = (nt << 4) + lcol;
            const float sclv = scl[gc], shfv = shf[gc], bias = b1[gc];
            const int kk = (nt4 << 4) + lcol;
#pragma unroll
            for (int r = 0; r < 4; ++r) {
                const int row = w * 16 + (quad << 2) + r;
                float v = acc[nt][r] + bias;
                float a = fmaxf(fmaf(v, sclv, shfv), 0.f);
                unsigned short hi = f2bf(a);
                As[row * 72 + kk] = hi;
                Bs[row * 72 + kk] = f2bf(a - bf2f(hi));
            }
        }
        // stage w2e half-K hi/lo (pre-split in ws): one uint4 per thread
        *(uint4*)&B2h[(t >> 3) * 72 + ((t & 7) << 3)] =
            *(const uint4*)(w2eh + (size_t)(t >> 3) * 128 + (h << 6) + ((t & 7) << 3));
        *(uint4*)&B2l[(t >> 3) * 72 + ((t & 7) << 3)] =
            *(const uint4*)(w2el + (size_t)(t >> 3) * 128 + (h << 6) + ((t & 7) << 3));
        __syncthreads();
#pragma unroll
        for (int kc = 0; kc < 2; ++kc) {
            const int ko = (kc << 5) + (quad << 3);
            const bf8 ah = *(const bf8*)&As[(w * 16 + lcol) * 72 + ko];
            const bf8 al = *(const bf8*)&Bs[(w * 16 + lcol) * 72 + ko];
            const bf8 bh0 = *(const bf8*)&B2h[lcol * 72 + ko];
            const bf8 bh1 = *(const bf8*)&B2h[(16 + lcol) * 72 + ko];
            const bf8 bl0 = *(const bf8*)&B2l[lcol * 72 + ko];
            const bf8 bl1 = *(const bf8*)&B2l[(16 + lcol) * 72 + ko];
            zacc[0] = __builtin_amdgcn_mfma_f32_16x16x32_bf16(ah, bh0, zacc[0], 0, 0, 0);
            zacc[0] = __builtin_amdgcn_mfma_f32_16x16x32_bf16(al, bh0, zacc[0], 0, 0, 0);
            zacc[0] = __builtin_amdgcn_mfma_f32_16x16x32_bf16(ah, bl0, zacc[0], 0, 0, 0);
            zacc[1] = __builtin_amdgcn_mfma_f32_16x16x32_bf16(ah, bh1, zacc[1], 0, 0, 0);
            zacc[1] = __builtin_amdgcn_mfma_f32_16x16x32_bf16(al, bh1, zacc[1], 0, 0, 0);
            zacc[1] = __builtin_amdgcn_mfma_f32_16x16x32_bf16(ah, bl1, zacc[1], 0, 0, 0);
        }
        __syncthreads();
    }
    // bias; fp32 z in regs; bf16 z -> zs (A-layout)
    const float b2lo = b2e[lcol], b2hi = b2e[16 + lcol];
    float zf0[4], zf1[4];
#pragma unroll
    for (int r = 0; r < 4; ++r) {
        float v0 = zacc[0][r] + b2lo;
        float v1 = zacc[1][r] + b2hi;
        zf0[r] = v0;
        zf1[r] = v1;
        int row = w * 16 + (quad << 2) + r;
        zs[row * 40 + lcol] = f2bf(v0);
        zs[row * 40 + 16 + lcol] = f2bf(v1);
    }
    __syncthreads();

    // --- quant sweep (bf16 proxy argmin) ---
    const bf8 af = *(const bf8*)&zs[(w * 16 + lcol) * 40 + (quad << 3)];
    float best[4];
    int bidx[4];
#pragma unroll
    for (int r = 0; r < 4; ++r) { best[r] = 3.4e38f; bidx[r] = 0; }
    const f4a zero4 = {0.f, 0.f, 0.f, 0.f};

    for (int cp = 0; cp < 4; ++cp) {
        if (cp) __syncthreads();
#pragma unroll
        for (int i = 0; i < 4; ++i) {
            int idx = (i << 8) + t;
            int r = idx >> 2, kq = (idx & 3) << 3;
            *(uint4*)&cs[r * 40 + kq] = *(const uint4*)(cbb + (size_t)((cp << 8) + r) * 32 + kq);
        }
        cn[t] = cn_g[(cp << 8) + t];
        __syncthreads();
        bf8 bb = *(const bf8*)&cs[lcol * 40 + (quad << 3)];
        float cnv = cn[lcol];
        for (int ch = 0; ch < 16; ++ch) {
            const int nn = ((ch + 1) & 15) << 4;
            const bf8 bb_n = *(const bf8*)&cs[(nn + lcol) * 40 + (quad << 3)];
            const float cn_n = cn[nn + lcol];
            const int cidx = (cp << 8) + (ch << 4) + lcol;
            f4a a = __builtin_amdgcn_mfma_f32_16x16x32_bf16(af, bb, zero4, 0, 0, 0);
#pragma unroll
            for (int r = 0; r < 4; ++r) {
                float d = fmaf(-2.f, a[r], cnv);
                if (d < best[r]) { best[r] = d; bidx[r] = cidx; }
            }
            bb = bb_n; cnv = cn_n;
        }
    }
#pragma unroll
    for (int off = 1; off < 16; off <<= 1) {
#pragma unroll
        for (int r = 0; r < 4; ++r) {
            float ob = __shfl_xor(best[r], off);
            int oi = __shfl_xor(bidx[r], off);
            if (ob < best[r] || (ob == best[r] && oi < bidx[r])) {
                best[r] = ob; bidx[r] = oi;
            }
        }
    }
    // exact fp32 distance of selected codeword (register z, fp32 cb)
    float lsum = 0.f;
#pragma unroll
    for (int r = 0; r < 4; ++r) {
        const int rowl = w * 16 + (quad << 2) + r;
        const int ti = bidx[r];
        const float* cp_ = cb + (size_t)ti * 32;
        float d0 = zf0[r] - cp_[lcol];
        float d1 = zf1[r] - cp_[16 + lcol];
        float p = fmaf(d0, d0, d1 * d1);
        p += __shfl_xor(p, 1); p += __shfl_xor(p, 2);
        p += __shfl_xor(p, 4); p += __shfl_xor(p, 8);
        if (lcol == 0) {
            topicsL[rowl] = ti;
            lsum += p;
        }
    }
    red[t] = lsum;
    __syncthreads();
    for (int s = 128; s > 0; s >>= 1) {
        if (t < s) red[t] += red[t + s];
        __syncthreads();
    }
    if (t == 0) atomicAdd(acc_g + 512, red[0]);

    // --- dec1: h2 = q@w1d + b1d (regs) + BN2 column stats ---
    *(uint4*)&W1dT[(t >> 1) * 40 + ((t & 1) << 3)] =
        *(const uint4*)(w1dTg + (size_t)(t >> 1) * 32 + ((t & 1) << 3));
    if (t < 128)
        *(uint4*)&Qs[(t >> 2) * 40 + ((t & 3) << 3)] =
            *(const uint4*)(cbb + (size_t)topicsL[t >> 2] * 32 + ((t & 3) << 3));
    __syncthreads();
    f4a dacc[8];
#pragma unroll
    for (int j = 0; j < 8; ++j) dacc[j] = (f4a){0.f, 0.f, 0.f, 0.f};
    const bf8 da = *(const bf8*)&Qs[(w * 16 + lcol) * 40 + (quad << 3)];
#pragma unroll
    for (int nt = 0; nt < 8; ++nt) {
        const bf8 bb = *(const bf8*)&W1dT[(nt * 16 + lcol) * 40 + (quad << 3)];
        dacc[nt] = __builtin_amdgcn_mfma_f32_16x16x32_bf16(da, bb, dacc[nt], 0, 0, 0);
    }
#pragma unroll
    for (int nt = 0; nt < 8; ++nt) {
        const int gc = (nt << 4) + lcol;
        const float bias = b1d[gc];
        float s = 0.f, ss = 0.f;
#pragma unroll
        for (int r = 0; r < 4; ++r) {
            float v = dacc[nt][r] + bias;
            dacc[nt][r] = v;   // keep h2 (with bias) in regs
            s += v;
            ss = fmaf(v, v, ss);
        }
        s += __shfl_xor(s, 16);  s += __shfl_xor(s, 32);
        ss += __shfl_xor(ss, 16); ss += __shfl_xor(ss, 32);
        if (quad == 0) { sst2[w * 128 + gc] = s; sst2[512 + w * 128 + gc] = ss; }
    }
    __syncthreads();
    if (t < 128) {
        atomicAdd(&acc_g[256 + t], sst2[t] + sst2[128 + t] + sst2[256 + t] + sst2[384 + t]);
        atomicAdd(&acc_g[384 + t], sst2[512 + t] + sst2[640 + t] + sst2[768 + t] + sst2[896 + t]);
    }
    gsync(bar, 2048);

    // ================= P3: BN2 -> dec2 -> sum((X_-X)^2) =================
    if (t < 128) {
        float mu = aload(&acc_g[256 + t]) * (1.f / 65536.f);
        float var = fmaf(-mu, mu, aload(&acc_g[384 + t]) * (1.f / 65536.f));
        float s = g2[t] * rsqrtf(var + 1e-5f);
        scl[t] = s;
        shf[t] = fmaf(-mu, s, be2[t]);
    }
    __syncthreads();
    // H2r = relu(bn2(h2)) -> Ad [64][136] bf16
#pragma unroll
    for (int nt = 0; nt < 8; ++nt) {
        const int gc = (nt << 4) + lcol;
        const float sclv = scl[gc], shfv = shf[gc];
#pragma unroll
        for (int r = 0; r < 4; ++r) {
            const int row = w * 16 + (quad << 2) + r;
            float hr = fmaxf(fmaf(dacc[nt][r], sclv, shfv), 0.f);
            Ad[row * 136 + gc] = f2bf(hr);
        }
    }
    __syncthreads();
    float l2 = 0.f;
    for (int nc = 0; nc < 4; ++nc) {      // 4 x 128 output cols
        f4a acc2[8];
#pragma unroll
        for (int j = 0; j < 8; ++j) acc2[j] = (f4a){0.f, 0.f, 0.f, 0.f};
        for (int kc = 0; kc < 4; ++kc) {  // 4 x 32 K
            if (nc | kc) __syncthreads();
#pragma unroll
            for (int i = 0; i < 2; ++i) { // Bsd <- w2dT chunk, coalesced uint4
                const int idx = (i << 8) + t;
                const int n = idx >> 2, u = idx & 3;
                *(uint4*)&Bsd[n * 40 + (u << 3)] =
                    *(const uint4*)(w2dT + (size_t)((nc << 7) + n) * 128 + (kc << 5) + (u << 3));
            }
            __syncthreads();
            const bf8 af0 = *(const bf8*)&Ad[(w * 16 + lcol) * 136 + (kc << 5) + (quad << 3)];
#pragma unroll
            for (int nt = 0; nt < 8; ++nt) {
                const bf8 bb = *(const bf8*)&Bsd[(nt * 16 + lcol) * 40 + (quad << 3)];
                acc2[nt] = __builtin_amdgcn_mfma_f32_16x16x32_bf16(af0, bb, acc2[nt], 0, 0, 0);
            }
        }
        // epilogue: direct (X_ - X)^2, X re-read L3-resident
#pragma unroll
        for (int nt = 0; nt < 8; ++nt) {
            const int gcol = (nc << 7) + (nt << 4) + lcol;
            const float bias = b2d[gcol];
            const int rbase = row0 + w * 16 + (quad << 2);
#pragma unroll
            for (int r = 0; r < 4; ++r) {
                const float val = acc2[nt][r] + bias;
                const float d = val - X[(size_t)(rbase + r) * 512 + gcol];
                l2 = fmaf(d, d, l2);
            }
        }
    }
    red[t] = l2;
    __syncthreads();
    for (int s = 128; s > 0; s >>= 1) {
        if (t < s) red[t] += red[t + s];
        __syncthreads();
    }
    if (t == 0) atomicAdd(acc_g + 513, red[0]);
}

// ======== K2: out = 2*z_loss + sqrt(sum((X_-X)^2)) ========
__global__ void k_final(const float* __restrict__ acc, float* __restrict__ out) {
    if (threadIdx.x == 0)
        out[0] = 2.f * acc[512] + sqrtf(acc[513]);
}

extern "C" void kernel_launch(void* const* d_in, const int* in_sizes, int n_in,
                              void* d_out, int out_size, void* d_ws, size_t ws_size,
                              hipStream_t stream) {
    const float* X       = (const float*)d_in[0];
    const float* enc_w1  = (const float*)d_in[1];
    const float* enc_b1  = (const float*)d_in[2];
    const float* enc_g1  = (const float*)d_in[3];
    const float* enc_be1 = (const float*)d_in[4];
    const float* enc_w2  = (const float*)d_in[5];
    const float* enc_b2  = (const float*)d_in[6];
    const float* dec_w1  = (const float*)d_in[7];
    const float* dec_b1  = (const float*)d_in[8];
    const float* dec_g1  = (const float*)d_in[9];
    const float* dec_be1 = (const float*)d_in[10];
    const float* dec_w2  = (const float*)d_in[11];
    const float* dec_b2  = (const float*)d_in[12];
    const float* cb      = (const float*)d_in[13];
    float* out = (float*)d_out;

    float* acc = (float*)d_ws;                                // 1024 f32 (incl. barrier)
    unsigned short* cbb = (unsigned short*)(acc + 1024);      // 1024*32 bf16
    float* cn_g = (float*)(cbb + 32768);                      // 1024 f32
    unsigned short* w1T   = (unsigned short*)(cn_g + 1024);   // [128][512] bf16
    unsigned short* w2dT  = w1T + 65536;                      // [512][128] bf16
    unsigned short* w1dTg = w2dT + 65536;                     // [128][32] bf16
    unsigned short* w2eh  = w1dTg + 4096;                     // [32][128] bf16
    unsigned short* w2el  = w2eh + 4096;                      // [32][128] bf16

    k_prep<<<87, 256, 0, stream>>>(cb, enc_w1, dec_w2, dec_w1, enc_w2,
                                   acc, cbb, cn_g, w1T, w2dT, w1dTg, w2eh, w2el);
    k_fused<<<1024, 256, 0, stream>>>(X, enc_b1, enc_g1, enc_be1, enc_b2,
                                      dec_b1, dec_g1, dec_be1, dec_b2,
                                      cb, cbb, cn_g, w1T, w2dT, w1dTg, w2eh, w2el,
                                      acc);
    k_final<<<1, 64, 0, stream>>>(acc, out);
}

// Round 6
// 522.617 us; speedup vs baseline: 1.2217x; 1.2217x over previous
//
#include <hip/hip_runtime.h>
#include <math.h>

// VQ-AE forward, single fused kernel + software grid barriers (R6).
// R4/R5 post-mortem: the gsync spin used ACQUIRE agent-scope loads; on gfx950
// (non-cross-coherent per-XCD L2s) each poll emits an L2 invalidation ->
// continuous invalidation storm while any block spins -> all "L2-resident"
// operands degrade to L3/HBM latency (R5: 284 GB/s, 1.9% MFMA, 491us).
// R6 fix: spin with RELAXED atomic loads (sc1, coherence-point served, NO
// invalidation); __threadfence() + relaxed fetch_add at arrival. All data
// crossing the barrier is written via device-scope atomicAdd and read via
// relaxed agent-scope atomic loads -> no acquire needed anywhere.
// Also restores P1's chunk+1 register prefetch (dropped by mistake in R5).
//
// Geometry: 1024 blocks x 256 thr, 64 rows/block, LDS 39.2KB -> 4 blocks/CU,
// launch_bounds(256,4). Weights pre-converted to bf16 in k_prep.
// Structure: P1 enc1 (h1 in regs) -> gsync -> P2 BN1+enc2(split-bf16)+quant+dec1
// (h2 in regs) -> gsync -> P3 BN2+dec2 + direct (X_-X)^2 (X re-read L3-resident).
// z-path accuracy-critical: h1 fp32 in regs, z via split-bf16 MFMA (3 products),
// exact fp32 selected-distance. Post-topics path single bf16.
//
// ws: acc[1024] f32 | cbb[1024*32] bf16 | cn_g[1024] f32 | w1T bf16[128][512]
//     | w2dT bf16[512][128] | w1dTg bf16[128][32] | w2eh/w2el bf16[32][128]
// acc: [0..127] sum1, [128..255] sumsq1, [256..383] sum2, [384..511] sumsq2,
//      [512] min-dist sum, [513] sum((X_-X)^2), [520] barrier counter (int)

typedef __attribute__((ext_vector_type(8))) short bf8;
typedef __attribute__((ext_vector_type(4))) float f4a;

__device__ __forceinline__ unsigned short f2bf(float f) {
    unsigned u = __float_as_uint(f);
    u += 0x7fffu + ((u >> 16) & 1u);   // RNE
    return (unsigned short)(u >> 16);
}
__device__ __forceinline__ float bf2f(unsigned short h) {
    return __uint_as_float((unsigned)h << 16);
}
__device__ __forceinline__ unsigned pack2(float a, float b) {
    return (unsigned)f2bf(a) | ((unsigned)f2bf(b) << 16);
}

// Monotonic software grid barrier, invalidation-free spin.
// Arrival: __threadfence (drain prior device-scope RMWs) + RELAXED fetch_add.
// Spin: RELAXED agent atomic load (sc1 -> coherence point, no cache inv).
// Post-barrier data reads use aload() (relaxed agent) -> coherent by construction.
__device__ __forceinline__ void gsync(int* cnt, int goal) {
    __syncthreads();
    if (threadIdx.x == 0) {
        __threadfence();
        __hip_atomic_fetch_add(cnt, 1, __ATOMIC_RELAXED, __HIP_MEMORY_SCOPE_AGENT);
        while (__hip_atomic_load(cnt, __ATOMIC_RELAXED, __HIP_MEMORY_SCOPE_AGENT) < goal)
            __builtin_amdgcn_s_sleep(8);
    }
    __syncthreads();
}
__device__ __forceinline__ float aload(const float* p) {
    return __hip_atomic_load(p, __ATOMIC_RELAXED, __HIP_MEMORY_SCOPE_AGENT);
}

// ======== K0: zero acc + codebook->bf16+norms + weight pre-conversion ========
__global__ __launch_bounds__(256) void k_prep(const float* __restrict__ cb,
                                              const float* __restrict__ w1,
                                              const float* __restrict__ w2d,
                                              const float* __restrict__ w1d,
                                              const float* __restrict__ w2e,
                                              float* __restrict__ acc,
                                              unsigned short* __restrict__ cbb,
                                              float* __restrict__ cn_g,
                                              unsigned short* __restrict__ w1T,
                                              unsigned short* __restrict__ w2dT,
                                              unsigned short* __restrict__ w1dTg,
                                              unsigned short* __restrict__ w2eh,
                                              unsigned short* __restrict__ w2el) {
    const int b = blockIdx.x, t = threadIdx.x;
    if (b < 4) {                       // codebook -> bf16 + fp32 norms
        const int cw = (b << 8) + t;
        const float* p = cb + (size_t)cw * 32;
        unsigned out[16];
        float n = 0.f;
#pragma unroll
        for (int i = 0; i < 8; ++i) {
            float4 v = *(const float4*)(p + (i << 2));
            n = fmaf(v.x, v.x, n); n = fmaf(v.y, v.y, n);
            n = fmaf(v.z, v.z, n); n = fmaf(v.w, v.w, n);
            out[2 * i]     = pack2(v.x, v.y);
            out[2 * i + 1] = pack2(v.z, v.w);
        }
#pragma unroll
        for (int i = 0; i < 4; ++i)
            *(uint4*)(cbb + (size_t)cw * 32 + (i << 3)) =
                make_uint4(out[4 * i], out[4 * i + 1], out[4 * i + 2], out[4 * i + 3]);
        cn_g[cw] = n;
    } else if (b == 4) {               // zero accumulators + barrier
        for (int i = t; i < 1024; i += 256) acc[i] = 0.f;
    } else if (b < 21) {               // w1T[n][k] <- w1[k][n] (16 blocks x 8 rows)
        const int n0 = (b - 5) << 3;
        for (int rr = 0; rr < 8; ++rr) {
            const int n = n0 + rr;
            w1T[(size_t)n * 512 + t]       = f2bf(w1[(size_t)t * 128 + n]);
            w1T[(size_t)n * 512 + 256 + t] = f2bf(w1[(size_t)(256 + t) * 128 + n]);
        }
    } else if (b < 85) {               // w2dT[n][k] <- w2d[k][n] (64 blocks x 8 rows)
        const int n0 = (b - 21) << 3;
        if (t < 128)
            for (int rr = 0; rr < 8; ++rr) {
                const int n = n0 + rr;
                w2dT[(size_t)n * 128 + t] = f2bf(w2d[(size_t)t * 512 + n]);
            }
    } else if (b == 85) {              // w1dTg[n][k] <- w1d[k][n], [128][32]
        for (int i = 0; i < 16; ++i) {
            const int idx = (i << 8) + t;
            const int n = idx >> 5, k = idx & 31;
            w1dTg[idx] = f2bf(w1d[(size_t)k * 128 + n]);
        }
    } else {                           // b==86: w2e hi/lo split [32 n][128 k]
        for (int i = 0; i < 16; ++i) {
            const int idx = (i << 8) + t;
            const int n = idx >> 7, k = idx & 127;
            const float f = w2e[(size_t)k * 32 + n];
            unsigned short hi = f2bf(f);
            w2eh[idx] = hi;
            w2el[idx] = f2bf(f - bf2f(hi));
        }
    }
}

// ======== K1: fused pipeline (1024 x 256, 4 blocks/CU, 64 rows/block) ========
// LDS pool 39168 B:
//  [0,27648)  region0:
//    P1:  As[64][72] @0 | Bs(w1T chunk)[128][72] @9216
//    P2a: Ash @0 | Asl @9216 | B2h[32][72] @18432 | B2l @23040
//    P2b: cs[256][40] @0 | cn f32[256] @20480
//    P2c: W1dT[128][40] @0 | Qs[64][40] @10240 | sst2 f32[1024] @15360
//    P3:  Ad[64][136] @0 | Bsd[128][40] @17408
//  [27648,32768) zs bf16[64][40] | [32768,33792) scl/shf | [33792,34048) topicsL
//  [34048,35072) red f32[256] | [35072,39168) sred f32[1024]
__global__ __launch_bounds__(256, 4) void k_fused(
    const float* __restrict__ X,
    const float* __restrict__ b1,
    const float* __restrict__ g1,
    const float* __restrict__ be1,
    const float* __restrict__ b2e,
    const float* __restrict__ b1d,
    const float* __restrict__ g2,
    const float* __restrict__ be2,
    const float* __restrict__ b2d,
    const float* __restrict__ cb,
    const unsigned short* __restrict__ cbb,
    const float* __restrict__ cn_g,
    const unsigned short* __restrict__ w1T,
    const unsigned short* __restrict__ w2dT,
    const unsigned short* __restrict__ w1dTg,
    const unsigned short* __restrict__ w2eh,
    const unsigned short* __restrict__ w2el,
    float* __restrict__ acc_g)
{
    __shared__ __align__(16) char pool[39168];
    unsigned short* As   = (unsigned short*)pool;               // P1 A / P2a Ash
    unsigned short* Bs   = (unsigned short*)(pool + 9216);      // P1 B / P2a Asl
    unsigned short* B2h  = (unsigned short*)(pool + 18432);
    unsigned short* B2l  = (unsigned short*)(pool + 23040);
    unsigned short* cs   = (unsigned short*)pool;
    float*          cn   = (float*)(pool + 20480);
    unsigned short* W1dT = (unsigned short*)pool;
    unsigned short* Qs   = (unsigned short*)(pool + 10240);
    float*          sst2 = (float*)(pool + 15360);
    unsigned short* Ad   = (unsigned short*)pool;               // P3 [64][136]
    unsigned short* Bsd  = (unsigned short*)(pool + 17408);     // P3 [128][40]
    unsigned short* zs   = (unsigned short*)(pool + 27648);
    float* scl     = (float*)(pool + 32768);
    float* shf     = (float*)(pool + 33280);
    int*   topicsL = (int*)(pool + 33792);
    float* red     = (float*)(pool + 34048);
    float* sred    = (float*)(pool + 35072);

    const int t = threadIdx.x;
    const int w = t >> 6, lane = t & 63, quad = lane >> 4, lcol = lane & 15;
    const int row0 = blockIdx.x << 6;    // 64 rows/block
    int* bar = (int*)(acc_g + 520);

    // ================= P1: h1 = X@w1 (regs) + BN1 column stats =================
    f4a acc[8];
#pragma unroll
    for (int j = 0; j < 8; ++j) acc[j] = (f4a){0.f, 0.f, 0.f, 0.f};

    const int arb = t >> 4;               // A: 16 rows per step
    const int akq = (t & 15) << 2;        // A k-quad
    const int bnr = t >> 3, bu = t & 7;   // B: row / uint4-slot

    float4 xa[4];
    uint4  wb[4];
    // prologue: chunk 0 into regs (prefetch pipeline)
#pragma unroll
    for (int i = 0; i < 4; ++i) {
        xa[i] = *(const float4*)(X + (size_t)(row0 + (i << 4) + arb) * 512 + akq);
        wb[i] = *(const uint4*)(w1T + (size_t)((i << 5) + bnr) * 512 + (bu << 3));
    }
    for (int c = 0; c < 8; ++c) {
        __syncthreads();
#pragma unroll
        for (int i = 0; i < 4; ++i) {     // staged regs -> LDS
            const int r = (i << 4) + arb;
            *(uint2*)&As[r * 72 + akq] = make_uint2(pack2(xa[i].x, xa[i].y), pack2(xa[i].z, xa[i].w));
            *(uint4*)&Bs[((i << 5) + bnr) * 72 + (bu << 3)] = wb[i];
        }
        __syncthreads();
        if (c < 7) {                      // issue chunk c+1 loads before MFMA
            const int k0n = (c + 1) << 6;
#pragma unroll
            for (int i = 0; i < 4; ++i) {
                xa[i] = *(const float4*)(X + (size_t)(row0 + (i << 4) + arb) * 512 + k0n + akq);
                wb[i] = *(const uint4*)(w1T + (size_t)((i << 5) + bnr) * 512 + k0n + (bu << 3));
            }
        }
#pragma unroll
        for (int ks = 0; ks < 2; ++ks) {
            const bf8 a0 = *(const bf8*)&As[(w * 16 + lcol) * 72 + (ks << 5) + (quad << 3)];
#pragma unroll
            for (int nt = 0; nt < 8; ++nt) {
                const bf8 bb = *(const bf8*)&Bs[(nt * 16 + lcol) * 72 + (ks << 5) + (quad << 3)];
                acc[nt] = __builtin_amdgcn_mfma_f32_16x16x32_bf16(a0, bb, acc[nt], 0, 0, 0);
            }
        }
    }
    // BN1 column stats (h1 never leaves registers)
#pragma unroll
    for (int nt = 0; nt < 8; ++nt) {
        const int gc = (nt << 4) + lcol;
        const float bias = b1[gc];
        float s = 0.f, ss = 0.f;
#pragma unroll
        for (int r = 0; r < 4; ++r) {
            float v = acc[nt][r] + bias;
            s += v;
            ss = fmaf(v, v, ss);
        }
        s += __shfl_xor(s, 16);  s += __shfl_xor(s, 32);
        ss += __shfl_xor(ss, 16); ss += __shfl_xor(ss, 32);
        if (quad == 0) { sred[w * 128 + gc] = s; sred[512 + w * 128 + gc] = ss; }
    }
    __syncthreads();
    if (t < 128) {
        atomicAdd(&acc_g[t], sred[t] + sred[128 + t] + sred[256 + t] + sred[384 + t]);
        atomicAdd(&acc_g[128 + t], sred[512 + t] + sred[640 + t] + sred[768 + t] + sred[896 + t]);
    }
    gsync(bar, 1024);

    // ================= P2: BN1 -> z (split-bf16) -> quant -> dec1 =================
    if (t < 128) {
        float mu = aload(&acc_g[t]) * (1.f / 65536.f);
        float var = fmaf(-mu, mu, aload(&acc_g[128 + t]) * (1.f / 65536.f));
        float s = g1[t] * rsqrtf(var + 1e-5f);
        scl[t] = s;
        shf[t] = fmaf(-mu, s, be1[t]);
    }
    __syncthreads();

    f4a zacc[2];
#pragma unroll
    for (int j = 0; j < 2; ++j) zacc[j] = (f4a){0.f, 0.f, 0.f, 0.f};

    // K=128 in two 64-wide chunks; A = relu(bn1(h1)) hi/lo from own regs
#pragma unroll
    for (int h = 0; h < 2; ++h) {
#pragma unroll
        for (int nt4 = 0; nt4 < 4; ++nt4) {
            const int nt = (h << 2) + nt4;
            const int gc = (nt << 4) + lcol;
            const float sclv = scl[gc], shfv = shf[gc], bias = b1[gc];
            const int kk = (nt4 << 4) + lcol;
#pragma unroll
            for (int r = 0; r < 4; ++r) {
                const int row = w * 16 + (quad << 2) + r;
                float v = acc[nt][r] + bias;
                float a = fmaxf(fmaf(v, sclv, shfv), 0.f);
                unsigned short hi = f2bf(a);
                As[row * 72 + kk] = hi;
                Bs[row * 72 + kk] = f2bf(a - bf2f(hi));
            }
        }
        // stage w2e half-K hi/lo (pre-split in ws): one uint4 per thread
        *(uint4*)&B2h[(t >> 3) * 72 + ((t & 7) << 3)] =
            *(const uint4*)(w2eh + (size_t)(t >> 3) * 128 + (h << 6) + ((t & 7) << 3));
        *(uint4*)&B2l[(t >> 3) * 72 + ((t & 7) << 3)] =
            *(const uint4*)(w2el + (size_t)(t >> 3) * 128 + (h << 6) + ((t & 7) << 3));
        __syncthreads();
#pragma unroll
        for (int kc = 0; kc < 2; ++kc) {
            const int ko = (kc << 5) + (quad << 3);
            const bf8 ah = *(const bf8*)&As[(w * 16 + lcol) * 72 + ko];
            const bf8 al = *(const bf8*)&Bs[(w * 16 + lcol) * 72 + ko];
            const bf8 bh0 = *(const bf8*)&B2h[lcol * 72 + ko];
            const bf8 bh1 = *(const bf8*)&B2h[(16 + lcol) * 72 + ko];
            const bf8 bl0 = *(const bf8*)&B2l[lcol * 72 + ko];
            const bf8 bl1 = *(const bf8*)&B2l[(16 + lcol) * 72 + ko];
            zacc[0] = __builtin_amdgcn_mfma_f32_16x16x32_bf16(ah, bh0, zacc[0], 0, 0, 0);
            zacc[0] = __builtin_amdgcn_mfma_f32_16x16x32_bf16(al, bh0, zacc[0], 0, 0, 0);
            zacc[0] = __builtin_amdgcn_mfma_f32_16x16x32_bf16(ah, bl0, zacc[0], 0, 0, 0);
            zacc[1] = __builtin_amdgcn_mfma_f32_16x16x32_bf16(ah, bh1, zacc[1], 0, 0, 0);
            zacc[1] = __builtin_amdgcn_mfma_f32_16x16x32_bf16(al, bh1, zacc[1], 0, 0, 0);
            zacc[1] = __builtin_amdgcn_mfma_f32_16x16x32_bf16(ah, bl1, zacc[1], 0, 0, 0);
        }
        __syncthreads();
    }
    // bias; fp32 z in regs; bf16 z -> zs (A-layout)
    const float b2lo = b2e[lcol], b2hi = b2e[16 + lcol];
    float zf0[4], zf1[4];
#pragma unroll
    for (int r = 0; r < 4; ++r) {
        float v0 = zacc[0][r] + b2lo;
        float v1 = zacc[1][r] + b2hi;
        zf0[r] = v0;
        zf1[r] = v1;
        int row = w * 16 + (quad << 2) + r;
        zs[row * 40 + lcol] = f2bf(v0);
        zs[row * 40 + 16 + lcol] = f2bf(v1);
    }
    __syncthreads();

    // --- quant sweep (bf16 proxy argmin) ---
    const bf8 af = *(const bf8*)&zs[(w * 16 + lcol) * 40 + (quad << 3)];
    float best[4];
    int bidx[4];
#pragma unroll
    for (int r = 0; r < 4; ++r) { best[r] = 3.4e38f; bidx[r] = 0; }
    const f4a zero4 = {0.f, 0.f, 0.f, 0.f};

    for (int cp = 0; cp < 4; ++cp) {
        if (cp) __syncthreads();
#pragma unroll
        for (int i = 0; i < 4; ++i) {
            int idx = (i << 8) + t;
            int r = idx >> 2, kq = (idx & 3) << 3;
            *(uint4*)&cs[r * 40 + kq] = *(const uint4*)(cbb + (size_t)((cp << 8) + r) * 32 + kq);
        }
        cn[t] = cn_g[(cp << 8) + t];
        __syncthreads();
        bf8 bb = *(const bf8*)&cs[lcol * 40 + (quad << 3)];
        float cnv = cn[lcol];
        for (int ch = 0; ch < 16; ++ch) {
            const int nn = ((ch + 1) & 15) << 4;
            const bf8 bb_n = *(const bf8*)&cs[(nn + lcol) * 40 + (quad << 3)];
            const float cn_n = cn[nn + lcol];
            const int cidx = (cp << 8) + (ch << 4) + lcol;
            f4a a = __builtin_amdgcn_mfma_f32_16x16x32_bf16(af, bb, zero4, 0, 0, 0);
#pragma unroll
            for (int r = 0; r < 4; ++r) {
                float d = fmaf(-2.f, a[r], cnv);
                if (d < best[r]) { best[r] = d; bidx[r] = cidx; }
            }
            bb = bb_n; cnv = cn_n;
        }
    }
#pragma unroll
    for (int off = 1; off < 16; off <<= 1) {
#pragma unroll
        for (int r = 0; r < 4; ++r) {
            float ob = __shfl_xor(best[r], off);
            int oi = __shfl_xor(bidx[r], off);
            if (ob < best[r] || (ob == best[r] && oi < bidx[r])) {
                best[r] = ob; bidx[r] = oi;
            }
        }
    }
    // exact fp32 distance of selected codeword (register z, fp32 cb)
    float lsum = 0.f;
#pragma unroll
    for (int r = 0; r < 4; ++r) {
        const int rowl = w * 16 + (quad << 2) + r;
        const int ti = bidx[r];
        const float* cp_ = cb + (size_t)ti * 32;
        float d0 = zf0[r] - cp_[lcol];
        float d1 = zf1[r] - cp_[16 + lcol];
        float p = fmaf(d0, d0, d1 * d1);
        p += __shfl_xor(p, 1); p += __shfl_xor(p, 2);
        p += __shfl_xor(p, 4); p += __shfl_xor(p, 8);
        if (lcol == 0) {
            topicsL[rowl] = ti;
            lsum += p;
        }
    }
    red[t] = lsum;
    __syncthreads();
    for (int s = 128; s > 0; s >>= 1) {
        if (t < s) red[t] += red[t + s];
        __syncthreads();
    }
    if (t == 0) atomicAdd(acc_g + 512, red[0]);

    // --- dec1: h2 = q@w1d + b1d (regs) + BN2 column stats ---
    *(uint4*)&W1dT[(t >> 1) * 40 + ((t & 1) << 3)] =
        *(const uint4*)(w1dTg + (size_t)(t >> 1) * 32 + ((t & 1) << 3));
    if (t < 128)
        *(uint4*)&Qs[(t >> 2) * 40 + ((t & 3) << 3)] =
            *(const uint4*)(cbb + (size_t)topicsL[t >> 2] * 32 + ((t & 3) << 3));
    __syncthreads();
    f4a dacc[8];
#pragma unroll
    for (int j = 0; j < 8; ++j) dacc[j] = (f4a){0.f, 0.f, 0.f, 0.f};
    const bf8 da = *(const bf8*)&Qs[(w * 16 + lcol) * 40 + (quad << 3)];
#pragma unroll
    for (int nt = 0; nt < 8; ++nt) {
        const bf8 bb = *(const bf8*)&W1dT[(nt * 16 + lcol) * 40 + (quad << 3)];
        dacc[nt] = __builtin_amdgcn_mfma_f32_16x16x32_bf16(da, bb, dacc[nt], 0, 0, 0);
    }
#pragma unroll
    for (int nt = 0; nt < 8; ++nt) {
        const int gc = (nt << 4) + lcol;
        const float bias = b1d[gc];
        float s = 0.f, ss = 0.f;
#pragma unroll
        for (int r = 0; r < 4; ++r) {
            float v = dacc[nt][r] + bias;
            dacc[nt][r] = v;   // keep h2 (with bias) in regs
            s += v;
            ss = fmaf(v, v, ss);
        }
        s += __shfl_xor(s, 16);  s += __shfl_xor(s, 32);
        ss += __shfl_xor(ss, 16); ss += __shfl_xor(ss, 32);
        if (quad == 0) { sst2[w * 128 + gc] = s; sst2[512 + w * 128 + gc] = ss; }
    }
    __syncthreads();
    if (t < 128) {
        atomicAdd(&acc_g[256 + t], sst2[t] + sst2[128 + t] + sst2[256 + t] + sst2[384 + t]);
        atomicAdd(&acc_g[384 + t], sst2[512 + t] + sst2[640 + t] + sst2[768 + t] + sst2[896 + t]);
    }
    gsync(bar, 2048);

    // ================= P3: BN2 -> dec2 -> sum((X_-X)^2) =================
    if (t < 128) {
        float mu = aload(&acc_g[256 + t]) * (1.f / 65536.f);
        float var = fmaf(-mu, mu, aload(&acc_g[384 + t]) * (1.f / 65536.f));
        float s = g2[t] * rsqrtf(var + 1e-5f);
        scl[t] = s;
        shf[t] = fmaf(-mu, s, be2[t]);
    }
    __syncthreads();
    // H2r = relu(bn2(h2)) -> Ad [64][136] bf16
#pragma unroll
    for (int nt = 0; nt < 8; ++nt) {
        const int gc = (nt << 4) + lcol;
        const float sclv = scl[gc], shfv = shf[gc];
#pragma unroll
        for (int r = 0; r < 4; ++r) {
            const int row = w * 16 + (quad << 2) + r;
            float hr = fmaxf(fmaf(dacc[nt][r], sclv, shfv), 0.f);
            Ad[row * 136 + gc] = f2bf(hr);
        }
    }
    __syncthreads();
    float l2 = 0.f;
    for (int nc = 0; nc < 4; ++nc) {      // 4 x 128 output cols
        f4a acc2[8];
#pragma unroll
        for (int j = 0; j < 8; ++j) acc2[j] = (f4a){0.f, 0.f, 0.f, 0.f};
        for (int kc = 0; kc < 4; ++kc) {  // 4 x 32 K
            if (nc | kc) __syncthreads();
#pragma unroll
            for (int i = 0; i < 2; ++i) { // Bsd <- w2dT chunk, coalesced uint4
                const int idx = (i << 8) + t;
                const int n = idx >> 2, u = idx & 3;
                *(uint4*)&Bsd[n * 40 + (u << 3)] =
                    *(const uint4*)(w2dT + (size_t)((nc << 7) + n) * 128 + (kc << 5) + (u << 3));
            }
            __syncthreads();
            const bf8 af0 = *(const bf8*)&Ad[(w * 16 + lcol) * 136 + (kc << 5) + (quad << 3)];
#pragma unroll
            for (int nt = 0; nt < 8; ++nt) {
                const bf8 bb = *(const bf8*)&Bsd[(nt * 16 + lcol) * 40 + (quad << 3)];
                acc2[nt] = __builtin_amdgcn_mfma_f32_16x16x32_bf16(af0, bb, acc2[nt], 0, 0, 0);
            }
        }
        // epilogue: direct (X_ - X)^2, X re-read L3-resident
#pragma unroll
        for (int nt = 0; nt < 8; ++nt) {
            const int gcol = (nc << 7) + (nt << 4) + lcol;
            const float bias = b2d[gcol];
            const int rbase = row0 + w * 16 + (quad << 2);
#pragma unroll
            for (int r = 0; r < 4; ++r) {
                const float val = acc2[nt][r] + bias;
                const float d = val - X[(size_t)(rbase + r) * 512 + gcol];
                l2 = fmaf(d, d, l2);
            }
        }
    }
    red[t] = l2;
    __syncthreads();
    for (int s = 128; s > 0; s >>= 1) {
        if (t < s) red[t] += red[t + s];
        __syncthreads();
    }
    if (t == 0) atomicAdd(acc_g + 513, red[0]);
}

// ======== K2: out = 2*z_loss + sqrt(sum((X_-X)^2)) ========
__global__ void k_final(const float* __restrict__ acc, float* __restrict__ out) {
    if (threadIdx.x == 0)
        out[0] = 2.f * acc[512] + sqrtf(acc[513]);
}

extern "C" void kernel_launch(void* const* d_in, const int* in_sizes, int n_in,
                              void* d_out, int out_size, void* d_ws, size_t ws_size,
                              hipStream_t stream) {
    const float* X       = (const float*)d_in[0];
    const float* enc_w1  = (const float*)d_in[1];
    const float* enc_b1  = (const float*)d_in[2];
    const float* enc_g1  = (const float*)d_in[3];
    const float* enc_be1 = (const float*)d_in[4];
    const float* enc_w2  = (const float*)d_in[5];
    const float* enc_b2  = (const float*)d_in[6];
    const float* dec_w1  = (const float*)d_in[7];
    const float* dec_b1  = (const float*)d_in[8];
    const float* dec_g1  = (const float*)d_in[9];
    const float* dec_be1 = (const float*)d_in[10];
    const float* dec_w2  = (const float*)d_in[11];
    const float* dec_b2  = (const float*)d_in[12];
    const float* cb      = (const float*)d_in[13];
    float* out = (float*)d_out;

    float* acc = (float*)d_ws;                                // 1024 f32 (incl. barrier)
    unsigned short* cbb = (unsigned short*)(acc + 1024);      // 1024*32 bf16
    float* cn_g = (float*)(cbb + 32768);                      // 1024 f32
    unsigned short* w1T   = (unsigned short*)(cn_g + 1024);   // [128][512] bf16
    unsigned short* w2dT  = w1T + 65536;                      // [512][128] bf16
    unsigned short* w1dTg = w2dT + 65536;                     // [128][32] bf16
    unsigned short* w2eh  = w1dTg + 4096;                     // [32][128] bf16
    unsigned short* w2el  = w2eh + 4096;                      // [32][128] bf16

    k_prep<<<87, 256, 0, stream>>>(cb, enc_w1, dec_w2, dec_w1, enc_w2,
                                   acc, cbb, cn_g, w1T, w2dT, w1dTg, w2eh, w2el);
    k_fused<<<1024, 256, 0, stream>>>(X, enc_b1, enc_g1, enc_be1, enc_b2,
                                      dec_b1, dec_g1, dec_be1, dec_b2,
                                      cb, cbb, cn_g, w1T, w2dT, w1dTg, w2eh, w2el,
                                      acc);
    k_final<<<1, 64, 0, stream>>>(acc, out);
}

// Round 7
// 443.743 us; speedup vs baseline: 1.4389x; 1.1777x over previous
//
#include <hip/hip_runtime.h>
#include <math.h>

// VQ-AE forward (R7): split pipeline + algebraic decoder collapse.
// Key fact: after quantization each row's decoder input is one of <=1024
// codewords -> h2 / BN2 stats / decoder output take <=1024 distinct values:
//   H2w = cb@dec_w1 + b1d                [1024][128]  (fp32, 4 MFLOP)
//   BN2: mu_c = (1/N) sum_k cnt_k H2w[k,c]  (cnt = topic histogram; exact)
//   Dw  = relu(bn2(H2w))@dec_w2 + b2d    [1024][512]  (fp32, 67 MFLOP)
//   sum((X_-X)^2) = sum_k cnt_k ||Dw[k]||^2 - 2 sum_n Dw[topic_n].X[n] + sum||X||^2
// This deletes the old 8.6-GFLOP k_dec2 GEMM and the h2b array entirely.
// (Difference-of-sums accuracy validated in R1; fp32 decoder is MORE accurate
// than the previous bf16 path.)
// Fused-kernel line (R3-R6) retired: grid-barrier spin + register pressure made
// every phase latency-bound (R6: 353us, 106MB scratch-spill writes).
//
// z-path unchanged & accuracy-critical: h1 fp32, z via split-bf16 MFMA
// (3 products), exact fp32 selected-distance.
//
// ws: acc[1024] f32 | cnt[1024] i32 | cbb[1024*32] bf16 | cn_g[1024] f32
//     | w1T bf16[128][512] | w2eh/w2el bf16[32][128] | topics i32[65536]
//     | h1 f32[65536*128] | H2w f32[1024*128] | Dw f32[1024*512]
// acc: [0..127] sum1, [128..255] sumsq1, [256..383] sum2w, [384..511] sumsq2w,
//      [512] z_loss, [513] sum cnt||Dw||^2, [514] cross, [515] sum||X||^2

typedef __attribute__((ext_vector_type(8))) short bf8;
typedef __attribute__((ext_vector_type(4))) float f4a;

__device__ __forceinline__ unsigned short f2bf(float f) {
    unsigned u = __float_as_uint(f);
    u += 0x7fffu + ((u >> 16) & 1u);   // RNE
    return (unsigned short)(u >> 16);
}
__device__ __forceinline__ float bf2f(unsigned short h) {
    return __uint_as_float((unsigned)h << 16);
}
__device__ __forceinline__ unsigned pack2(float a, float b) {
    return (unsigned)f2bf(a) | ((unsigned)f2bf(b) << 16);
}

// ======== K0: zero acc/cnt + codebook->bf16+norms + w1T / w2e-split prep ========
__global__ __launch_bounds__(256) void k_prep(const float* __restrict__ cb,
                                              const float* __restrict__ w1,
                                              const float* __restrict__ w2e,
                                              float* __restrict__ acc,
                                              int* __restrict__ cnt,
                                              unsigned short* __restrict__ cbb,
                                              float* __restrict__ cn_g,
                                              unsigned short* __restrict__ w1T,
                                              unsigned short* __restrict__ w2eh,
                                              unsigned short* __restrict__ w2el) {
    const int b = blockIdx.x, t = threadIdx.x;
    if (b < 4) {                       // codebook -> bf16 + fp32 norms
        const int cw = (b << 8) + t;
        const float* p = cb + (size_t)cw * 32;
        unsigned out[16];
        float n = 0.f;
#pragma unroll
        for (int i = 0; i < 8; ++i) {
            float4 v = *(const float4*)(p + (i << 2));
            n = fmaf(v.x, v.x, n); n = fmaf(v.y, v.y, n);
            n = fmaf(v.z, v.z, n); n = fmaf(v.w, v.w, n);
            out[2 * i]     = pack2(v.x, v.y);
            out[2 * i + 1] = pack2(v.z, v.w);
        }
#pragma unroll
        for (int i = 0; i < 4; ++i)
            *(uint4*)(cbb + (size_t)cw * 32 + (i << 3)) =
                make_uint4(out[4 * i], out[4 * i + 1], out[4 * i + 2], out[4 * i + 3]);
        cn_g[cw] = n;
    } else if (b == 4) {               // zero accumulators + histogram
        for (int i = t; i < 1024; i += 256) { acc[i] = 0.f; cnt[i] = 0; }
    } else if (b < 21) {               // w1T[n][k] <- bf16(w1[k][n])
        const int n0 = (b - 5) << 3;
        for (int rr = 0; rr < 8; ++rr) {
            const int n = n0 + rr;
            w1T[(size_t)n * 512 + t]       = f2bf(w1[(size_t)t * 128 + n]);
            w1T[(size_t)n * 512 + 256 + t] = f2bf(w1[(size_t)(256 + t) * 128 + n]);
        }
    } else {                           // b==21: w2e hi/lo split [32 n][128 k]
        for (int i = 0; i < 16; ++i) {
            const int idx = (i << 8) + t;
            const int n = idx >> 7, k = idx & 127;
            const float f = w2e[(size_t)k * 32 + n];
            unsigned short hi = f2bf(f);
            w2eh[idx] = hi;
            w2el[idx] = f2bf(f - bf2f(hi));
        }
    }
}

// ======== K1: h1 = fp32(X@w1 + b1), BN1 column stats, sum||X||^2 ========
// 512 blocks x 256 thr, 128 rows/block; bf16 B from w1T (coalesced uint4),
// A-tile register prefetch of chunk c+1.
__global__ __launch_bounds__(256, 3) void k_enc1(const float* __restrict__ X,
                                                 const unsigned short* __restrict__ w1T,
                                                 const float* __restrict__ b1,
                                                 float* __restrict__ h1,
                                                 float* __restrict__ acc_g) {
    __shared__ unsigned short As[128 * 72];
    __shared__ unsigned short Bs[128 * 72];
    __shared__ float sred[1024];
    const int t = threadIdx.x;
    const int w = t >> 6, lane = t & 63, quad = lane >> 4, lcol = lane & 15;
    const int row0 = blockIdx.x << 7;

    f4a acc[2][8];
#pragma unroll
    for (int i = 0; i < 2; ++i)
#pragma unroll
        for (int j = 0; j < 8; ++j) acc[i][j] = (f4a){0.f, 0.f, 0.f, 0.f};

    const int arb = t >> 4;               // A: 16 rows per i-step
    const int akq = (t & 15) << 2;        // A k-quad
    const int bnr = t >> 3, bks = (t & 7) << 3;   // B: row / 8-halfword slot

    float4 xa[8];
    float s2 = 0.f;
#pragma unroll
    for (int i = 0; i < 8; ++i)
        xa[i] = *(const float4*)(X + (size_t)(row0 + (i << 4) + arb) * 512 + akq);

    for (int c = 0; c < 8; ++c) {
        const int k0 = c << 6;
        __syncthreads();
#pragma unroll
        for (int i = 0; i < 8; ++i) {     // A regs -> bf16 LDS (+ ||X||^2)
            const float4 v = xa[i];
            s2 = fmaf(v.x, v.x, s2); s2 = fmaf(v.y, v.y, s2);
            s2 = fmaf(v.z, v.z, s2); s2 = fmaf(v.w, v.w, s2);
            *(uint2*)&As[((i << 4) + arb) * 72 + akq] =
                make_uint2(pack2(v.x, v.y), pack2(v.z, v.w));
        }
#pragma unroll
        for (int i = 0; i < 4; ++i) {     // B: w1T chunk, coalesced uint4
            const int n = (i << 5) + bnr;
            *(uint4*)&Bs[n * 72 + bks] = *(const uint4*)(w1T + (size_t)n * 512 + k0 + bks);
        }
        __syncthreads();
        if (c < 7) {                      // prefetch next A chunk before MFMA
            const int k0n = k0 + 64;
#pragma unroll
            for (int i = 0; i < 8; ++i)
                xa[i] = *(const float4*)(X + (size_t)(row0 + (i << 4) + arb) * 512 + k0n + akq);
        }
#pragma unroll
        for (int ks = 0; ks < 2; ++ks) {
            const bf8 a0 = *(const bf8*)&As[(w * 32 + lcol) * 72 + (ks << 5) + (quad << 3)];
            const bf8 a1 = *(const bf8*)&As[(w * 32 + 16 + lcol) * 72 + (ks << 5) + (quad << 3)];
#pragma unroll
            for (int nt = 0; nt < 8; ++nt) {
                const bf8 bb = *(const bf8*)&Bs[(nt * 16 + lcol) * 72 + (ks << 5) + (quad << 3)];
                acc[0][nt] = __builtin_amdgcn_mfma_f32_16x16x32_bf16(a0, bb, acc[0][nt], 0, 0, 0);
                acc[1][nt] = __builtin_amdgcn_mfma_f32_16x16x32_bf16(a1, bb, acc[1][nt], 0, 0, 0);
            }
        }
    }
    // epilogue: h1 fp32 store + BN1 column stats
#pragma unroll
    for (int nt = 0; nt < 8; ++nt) {
        const int gc = (nt << 4) + lcol;
        const float bias = b1[gc];
        float s = 0.f, ss = 0.f;
#pragma unroll
        for (int mt = 0; mt < 2; ++mt) {
            const int rbase = row0 + w * 32 + mt * 16 + (quad << 2);
#pragma unroll
            for (int r = 0; r < 4; ++r) {
                float v = acc[mt][nt][r] + bias;
                h1[(size_t)(rbase + r) * 128 + gc] = v;
                s += v;
                ss = fmaf(v, v, ss);
            }
        }
        s += __shfl_xor(s, 16);  s += __shfl_xor(s, 32);
        ss += __shfl_xor(ss, 16); ss += __shfl_xor(ss, 32);
        if (quad == 0) { sred[w * 128 + gc] = s; sred[512 + w * 128 + gc] = ss; }
    }
    s2 += __shfl_xor(s2, 1);  s2 += __shfl_xor(s2, 2);  s2 += __shfl_xor(s2, 4);
    s2 += __shfl_xor(s2, 8);  s2 += __shfl_xor(s2, 16); s2 += __shfl_xor(s2, 32);
    if (lane == 0) atomicAdd(&acc_g[515], s2);
    __syncthreads();
    if (t < 128) {
        atomicAdd(&acc_g[t], sred[t] + sred[128 + t] + sred[256 + t] + sred[384 + t]);
        atomicAdd(&acc_g[128 + t], sred[512 + t] + sred[640 + t] + sred[768 + t] + sred[896 + t]);
    }
}

// ======== K2: BN1 -> z (split-bf16 MFMA) -> quantize: topics, histogram, z_loss ========
// 1024 blocks x 256 thr, 64 rows/block. No dec1, no h2 materialization.
// LDS pool 35072 B:
//   Ash @0 (9216) | Asl @9216 (9216) | B2h @18432 (4608) | B2l @23040 (4608)
//   overlays (post-z): cs @0 (20480) | cn @20480 (1024)
//   zs @27648 (5120) | scl @32768 | shf @33280 | (unused @33792) | red @34048
__global__ __launch_bounds__(256, 4) void k_quant(const float* __restrict__ h1,
                                                  const float* __restrict__ g1,
                                                  const float* __restrict__ be1,
                                                  const float* __restrict__ b2e,
                                                  const float* __restrict__ cb,
                                                  const unsigned short* __restrict__ cbb,
                                                  const float* __restrict__ cn_g,
                                                  const unsigned short* __restrict__ w2eh,
                                                  const unsigned short* __restrict__ w2el,
                                                  int* __restrict__ topics_g,
                                                  int* __restrict__ cnt,
                                                  float* __restrict__ acc_g) {
    __shared__ __align__(16) char pool[35072];
    unsigned short* Ash = (unsigned short*)pool;
    unsigned short* Asl = (unsigned short*)(pool + 9216);
    unsigned short* B2h = (unsigned short*)(pool + 18432);
    unsigned short* B2l = (unsigned short*)(pool + 23040);
    unsigned short* cs  = (unsigned short*)pool;
    float*          cn  = (float*)(pool + 20480);
    unsigned short* zs  = (unsigned short*)(pool + 27648);
    float* scl = (float*)(pool + 32768);
    float* shf = (float*)(pool + 33280);
    float* red = (float*)(pool + 34048);

    const int t = threadIdx.x;
    const int w = t >> 6, lane = t & 63, quad = lane >> 4, lcol = lane & 15;
    const int row0 = blockIdx.x << 6;

    if (t < 128) {   // BN1 params (stats complete: kernel boundary)
        float mu = acc_g[t] * (1.f / 65536.f);
        float var = fmaf(-mu, mu, acc_g[128 + t] * (1.f / 65536.f));
        float s = g1[t] * rsqrtf(var + 1e-5f);
        scl[t] = s;
        shf[t] = fmaf(-mu, s, be1[t]);
    }
    __syncthreads();

    f4a zacc[2];
#pragma unroll
    for (int j = 0; j < 2; ++j) zacc[j] = (f4a){0.f, 0.f, 0.f, 0.f};

    const int rb = t >> 4;
    const int kq = (t & 15) << 2;
#pragma unroll
    for (int h = 0; h < 2; ++h) {
        // stage A = relu(bn1(h1 tile)) hi/lo, cols [64h, 64h+64)
        const int gk = (h << 6) + kq;
        const float4 sc = *(const float4*)&scl[gk];
        const float4 sh = *(const float4*)&shf[gk];
#pragma unroll
        for (int i = 0; i < 4; ++i) {
            const int r = (i << 4) + rb;
            float4 v = *(const float4*)(h1 + (size_t)(row0 + r) * 128 + gk);
            float a0 = fmaxf(fmaf(v.x, sc.x, sh.x), 0.f);
            float a1 = fmaxf(fmaf(v.y, sc.y, sh.y), 0.f);
            float a2 = fmaxf(fmaf(v.z, sc.z, sh.z), 0.f);
            float a3 = fmaxf(fmaf(v.w, sc.w, sh.w), 0.f);
            unsigned short h0 = f2bf(a0), h1u = f2bf(a1), h2u = f2bf(a2), h3 = f2bf(a3);
            *(uint2*)&Ash[r * 72 + kq] = make_uint2(
                (unsigned)h0 | ((unsigned)h1u << 16), (unsigned)h2u | ((unsigned)h3 << 16));
            *(uint2*)&Asl[r * 72 + kq] = make_uint2(
                (unsigned)f2bf(a0 - bf2f(h0)) | ((unsigned)f2bf(a1 - bf2f(h1u)) << 16),
                (unsigned)f2bf(a2 - bf2f(h2u)) | ((unsigned)f2bf(a3 - bf2f(h3)) << 16));
        }
        // stage w2e half-K hi/lo (pre-split)
        *(uint4*)&B2h[(t >> 3) * 72 + ((t & 7) << 3)] =
            *(const uint4*)(w2eh + (size_t)(t >> 3) * 128 + (h << 6) + ((t & 7) << 3));
        *(uint4*)&B2l[(t >> 3) * 72 + ((t & 7) << 3)] =
            *(const uint4*)(w2el + (size_t)(t >> 3) * 128 + (h << 6) + ((t & 7) << 3));
        __syncthreads();
#pragma unroll
        for (int kc = 0; kc < 2; ++kc) {
            const int ko = (kc << 5) + (quad << 3);
            const bf8 ah = *(const bf8*)&Ash[(w * 16 + lcol) * 72 + ko];
            const bf8 al = *(const bf8*)&Asl[(w * 16 + lcol) * 72 + ko];
            const bf8 bh0 = *(const bf8*)&B2h[lcol * 72 + ko];
            const bf8 bh1 = *(const bf8*)&B2h[(16 + lcol) * 72 + ko];
            const bf8 bl0 = *(const bf8*)&B2l[lcol * 72 + ko];
            const bf8 bl1 = *(const bf8*)&B2l[(16 + lcol) * 72 + ko];
            zacc[0] = __builtin_amdgcn_mfma_f32_16x16x32_bf16(ah, bh0, zacc[0], 0, 0, 0);
            zacc[0] = __builtin_amdgcn_mfma_f32_16x16x32_bf16(al, bh0, zacc[0], 0, 0, 0);
            zacc[0] = __builtin_amdgcn_mfma_f32_16x16x32_bf16(ah, bl0, zacc[0], 0, 0, 0);
            zacc[1] = __builtin_amdgcn_mfma_f32_16x16x32_bf16(ah, bh1, zacc[1], 0, 0, 0);
            zacc[1] = __builtin_amdgcn_mfma_f32_16x16x32_bf16(al, bh1, zacc[1], 0, 0, 0);
            zacc[1] = __builtin_amdgcn_mfma_f32_16x16x32_bf16(ah, bl1, zacc[1], 0, 0, 0);
        }
        __syncthreads();
    }
    // bias; fp32 z in regs; bf16 z -> zs (A-layout)
    const float b2lo = b2e[lcol], b2hi = b2e[16 + lcol];
    float zf0[4], zf1[4];
#pragma unroll
    for (int r = 0; r < 4; ++r) {
        float v0 = zacc[0][r] + b2lo;
        float v1 = zacc[1][r] + b2hi;
        zf0[r] = v0;
        zf1[r] = v1;
        int row = w * 16 + (quad << 2) + r;
        zs[row * 40 + lcol] = f2bf(v0);
        zs[row * 40 + 16 + lcol] = f2bf(v1);
    }
    __syncthreads();

    // quant sweep (bf16 proxy argmin)
    const bf8 af = *(const bf8*)&zs[(w * 16 + lcol) * 40 + (quad << 3)];
    float best[4];
    int bidx[4];
#pragma unroll
    for (int r = 0; r < 4; ++r) { best[r] = 3.4e38f; bidx[r] = 0; }
    const f4a zero4 = {0.f, 0.f, 0.f, 0.f};

    for (int cp = 0; cp < 4; ++cp) {
        if (cp) __syncthreads();
#pragma unroll
        for (int i = 0; i < 4; ++i) {
            int idx = (i << 8) + t;
            int r = idx >> 2, kq2 = (idx & 3) << 3;
            *(uint4*)&cs[r * 40 + kq2] = *(const uint4*)(cbb + (size_t)((cp << 8) + r) * 32 + kq2);
        }
        cn[t] = cn_g[(cp << 8) + t];
        __syncthreads();
        bf8 bb = *(const bf8*)&cs[lcol * 40 + (quad << 3)];
        float cnv = cn[lcol];
        for (int ch = 0; ch < 16; ++ch) {
            const int nn = ((ch + 1) & 15) << 4;
            const bf8 bb_n = *(const bf8*)&cs[(nn + lcol) * 40 + (quad << 3)];
            const float cn_n = cn[nn + lcol];
            const int cidx = (cp << 8) + (ch << 4) + lcol;
            f4a a = __builtin_amdgcn_mfma_f32_16x16x32_bf16(af, bb, zero4, 0, 0, 0);
#pragma unroll
            for (int r = 0; r < 4; ++r) {
                float d = fmaf(-2.f, a[r], cnv);
                if (d < best[r]) { best[r] = d; bidx[r] = cidx; }
            }
            bb = bb_n; cnv = cn_n;
        }
    }
#pragma unroll
    for (int off = 1; off < 16; off <<= 1) {
#pragma unroll
        for (int r = 0; r < 4; ++r) {
            float ob = __shfl_xor(best[r], off);
            int oi = __shfl_xor(bidx[r], off);
            if (ob < best[r] || (ob == best[r] && oi < bidx[r])) {
                best[r] = ob; bidx[r] = oi;
            }
        }
    }
    // exact fp32 distance + topics + histogram
    float lsum = 0.f;
#pragma unroll
    for (int r = 0; r < 4; ++r) {
        const int rowl = w * 16 + (quad << 2) + r;
        const int ti = bidx[r];
        const float* cp_ = cb + (size_t)ti * 32;
        float d0 = zf0[r] - cp_[lcol];
        float d1 = zf1[r] - cp_[16 + lcol];
        float p = fmaf(d0, d0, d1 * d1);
        p += __shfl_xor(p, 1); p += __shfl_xor(p, 2);
        p += __shfl_xor(p, 4); p += __shfl_xor(p, 8);
        if (lcol == 0) {
            topics_g[row0 + rowl] = ti;
            atomicAdd(&cnt[ti], 1);
            lsum += p;
        }
    }
    red[t] = lsum;
    __syncthreads();
    for (int s = 128; s > 0; s >>= 1) {
        if (t < s) red[t] += red[t + s];
        __syncthreads();
    }
    if (t == 0) atomicAdd(acc_g + 512, red[0]);
}

// ======== K3a: H2w = cb@dec_w1 + b1d (fp32) + cnt-weighted BN2 sums ========
// 64 blocks x 256 thr; block covers 16 codewords.
__global__ __launch_bounds__(256, 4) void k_code1(const float* __restrict__ cb,
                                                  const float* __restrict__ w1d,
                                                  const float* __restrict__ b1d,
                                                  const int* __restrict__ cnt,
                                                  float* __restrict__ H2w,
                                                  float* __restrict__ acc_g) {
    const int t = threadIdx.x;
    const int k0 = blockIdx.x << 4;
    const int c = t & 127, half = t >> 7;
    const float bias = b1d[c];
    float ps = 0.f, pss = 0.f;
#pragma unroll
    for (int jr = 0; jr < 8; ++jr) {
        const int k = k0 + (half << 3) + jr;
        float a = bias;
        const float* cr = cb + (size_t)k * 32;
#pragma unroll
        for (int j = 0; j < 32; ++j)
            a = fmaf(cr[j], w1d[(size_t)j * 128 + c], a);
        H2w[(size_t)k * 128 + c] = a;
        const float cf = (float)cnt[k];
        ps = fmaf(cf, a, ps);
        pss = fmaf(cf * a, a, pss);
    }
    atomicAdd(&acc_g[256 + c], ps);
    atomicAdd(&acc_g[384 + c], pss);
}

// ======== K3b: Dw = relu(bn2(H2w))@dec_w2 + b2d (fp32) + sum cnt||Dw||^2 ========
// 128 blocks x 256 thr; block covers 8 codewords; single pass over w2d.
__global__ __launch_bounds__(256, 4) void k_code2(const float* __restrict__ H2w,
                                                  const float* __restrict__ w2d,
                                                  const float* __restrict__ b2d,
                                                  const float* __restrict__ g2,
                                                  const float* __restrict__ be2,
                                                  const int* __restrict__ cnt,
                                                  float* __restrict__ Dw,
                                                  float* __restrict__ acc_g) {
    __shared__ float Hr[8][128];
    __shared__ float scl[128], shf[128];
    __shared__ float red[256];
    const int t = threadIdx.x;
    const int k0 = blockIdx.x << 3;
    if (t < 128) {
        float mu = acc_g[256 + t] * (1.f / 65536.f);
        float var = fmaf(-mu, mu, acc_g[384 + t] * (1.f / 65536.f));
        float s = g2[t] * rsqrtf(var + 1e-5f);
        scl[t] = s;
        shf[t] = fmaf(-mu, s, be2[t]);
    }
    __syncthreads();
#pragma unroll
    for (int i = 0; i < 4; ++i) {
        const int idx = (i << 8) + t;
        const int kk = idx >> 7, j = idx & 127;
        const float v = H2w[(size_t)(k0 + kk) * 128 + j];
        Hr[kk][j] = fmaxf(fmaf(v, scl[j], shf[j]), 0.f);
    }
    __syncthreads();
    float a0[8], a1[8];
#pragma unroll
    for (int kk = 0; kk < 8; ++kk) { a0[kk] = 0.f; a1[kk] = 0.f; }
    for (int j = 0; j < 128; ++j) {
        const float w0 = w2d[(size_t)j * 512 + t];
        const float w1v = w2d[(size_t)j * 512 + 256 + t];
#pragma unroll
        for (int kk = 0; kk < 8; ++kk) {
            const float h = Hr[kk][j];
            a0[kk] = fmaf(h, w0, a0[kk]);
            a1[kk] = fmaf(h, w1v, a1[kk]);
        }
    }
    const float bb0 = b2d[t], bb1 = b2d[256 + t];
    float pd = 0.f;
#pragma unroll
    for (int kk = 0; kk < 8; ++kk) {
        const float cf = (float)cnt[k0 + kk];
        const float v0 = a0[kk] + bb0;
        const float v1 = a1[kk] + bb1;
        Dw[(size_t)(k0 + kk) * 512 + t] = v0;
        Dw[(size_t)(k0 + kk) * 512 + 256 + t] = v1;
        pd += cf * fmaf(v0, v0, v1 * v1);
    }
    red[t] = pd;
    __syncthreads();
    for (int s = 128; s > 0; s >>= 1) {
        if (t < s) red[t] += red[t + s];
        __syncthreads();
    }
    if (t == 0) atomicAdd(acc_g + 513, red[0]);
}

// ======== K4: cross = sum_n Dw[topic_n].X[n]  (X L3-resident, Dw L2-resident) ========
// 1024 blocks x 256 thr, 64 rows/block, 16 rows/wave, one row per wave-step.
__global__ __launch_bounds__(256, 8) void k_cross(const float* __restrict__ X,
                                                  const float* __restrict__ Dw,
                                                  const int* __restrict__ topics_g,
                                                  float* __restrict__ acc_g) {
    const int t = threadIdx.x;
    const int w = t >> 6, lane = t & 63;
    const int row0 = (blockIdx.x << 6) + (w << 4);
    float cr = 0.f;
#pragma unroll 4
    for (int i = 0; i < 16; ++i) {
        const int row = row0 + i;
        const int tp = topics_g[row];
        const float* xp = X + (size_t)row * 512 + (lane << 3);
        const float* dp = Dw + (size_t)tp * 512 + (lane << 3);
        float4 x0 = *(const float4*)xp;
        float4 x1 = *(const float4*)(xp + 4);
        float4 d0 = *(const float4*)dp;
        float4 d1 = *(const float4*)(dp + 4);
        cr = fmaf(x0.x, d0.x, cr); cr = fmaf(x0.y, d0.y, cr);
        cr = fmaf(x0.z, d0.z, cr); cr = fmaf(x0.w, d0.w, cr);
        cr = fmaf(x1.x, d1.x, cr); cr = fmaf(x1.y, d1.y, cr);
        cr = fmaf(x1.z, d1.z, cr); cr = fmaf(x1.w, d1.w, cr);
    }
    cr += __shfl_xor(cr, 1);  cr += __shfl_xor(cr, 2);  cr += __shfl_xor(cr, 4);
    cr += __shfl_xor(cr, 8);  cr += __shfl_xor(cr, 16); cr += __shfl_xor(cr, 32);
    if (lane == 0) atomicAdd(acc_g + 514, cr);
}

// ======== K5: out = 2*z_loss + sqrt(sumDw2 - 2*cross + xnorm) ========
__global__ void k_final(const float* __restrict__ acc, float* __restrict__ out) {
    if (threadIdx.x == 0)
        out[0] = 2.f * acc[512] + sqrtf(acc[513] - 2.f * acc[514] + acc[515]);
}

extern "C" void kernel_launch(void* const* d_in, const int* in_sizes, int n_in,
                              void* d_out, int out_size, void* d_ws, size_t ws_size,
                              hipStream_t stream) {
    const float* X       = (const float*)d_in[0];
    const float* enc_w1  = (const float*)d_in[1];
    const float* enc_b1  = (const float*)d_in[2];
    const float* enc_g1  = (const float*)d_in[3];
    const float* enc_be1 = (const float*)d_in[4];
    const float* enc_w2  = (const float*)d_in[5];
    const float* enc_b2  = (const float*)d_in[6];
    const float* dec_w1  = (const float*)d_in[7];
    const float* dec_b1  = (const float*)d_in[8];
    const float* dec_g1  = (const float*)d_in[9];
    const float* dec_be1 = (const float*)d_in[10];
    const float* dec_w2  = (const float*)d_in[11];
    const float* dec_b2  = (const float*)d_in[12];
    const float* cb      = (const float*)d_in[13];
    float* out = (float*)d_out;

    float* acc = (float*)d_ws;                                // 1024 f32
    int* cnt = (int*)(acc + 1024);                            // 1024 i32
    unsigned short* cbb = (unsigned short*)(cnt + 1024);      // 1024*32 bf16
    float* cn_g = (float*)(cbb + 32768);                      // 1024 f32
    unsigned short* w1T  = (unsigned short*)(cn_g + 1024);    // [128][512] bf16
    unsigned short* w2eh = w1T + 65536;                       // [32][128] bf16
    unsigned short* w2el = w2eh + 4096;                       // [32][128] bf16
    int* topics = (int*)(w2el + 4096);                        // 65536 i32
    float* h1 = (float*)(topics + 65536);                     // [65536][128] f32
    float* H2w = h1 + (size_t)65536 * 128;                    // [1024][128] f32
    float* Dw = H2w + 1024 * 128;                             // [1024][512] f32

    k_prep<<<22, 256, 0, stream>>>(cb, enc_w1, enc_w2, acc, cnt, cbb, cn_g,
                                   w1T, w2eh, w2el);
    k_enc1<<<512, 256, 0, stream>>>(X, w1T, enc_b1, h1, acc);
    k_quant<<<1024, 256, 0, stream>>>(h1, enc_g1, enc_be1, enc_b2, cb, cbb, cn_g,
                                      w2eh, w2el, topics, cnt, acc);
    k_code1<<<64, 256, 0, stream>>>(cb, dec_w1, dec_b1, cnt, H2w, acc);
    k_code2<<<128, 256, 0, stream>>>(H2w, dec_w2, dec_b2, dec_g1, dec_be1, cnt, Dw, acc);
    k_cross<<<1024, 256, 0, stream>>>(X, Dw, topics, acc);
    k_final<<<1, 64, 0, stream>>>(acc, out);
}

// Round 8
// 377.083 us; speedup vs baseline: 1.6932x; 1.1768x over previous
//
#include <hip/hip_runtime.h>
#include <math.h>

// VQ-AE forward (R8): R7 pipeline + ATOMIC-SERIALIZATION FIX.
// R7 post-mortem: k_quant 112us with all pipes <10% busy and ~20MB traffic --
// work accounts for ~10us. Hidden cost = same-address device atomics serializing
// at the coherence point (~40-80ns each): quant's 1024 z_loss + 65536 cnt
// atomics, enc1's 2048 wave-atomics to acc[515], cross's 4096 to acc[514].
// (Retro-evidence: R0 enc1 [no s2 atomics] was fast; R1 added per-wave s2/sb
// atomics and enc1 ballooned.)
// R8: hierarchical reduction everywhere -- wave shuffle -> block LDS reduce ->
// ONE plain per-block store -> tiny summation kernels (k_stats, k_hist) or
// k_final. Histogram: per-block LDS hist -> plain 4KB row flush -> k_hist sums.
// Column stats: plain colstat[block][256] -> k_stats. code1 at 8 blocks keeps
// 16/addr atomics (negligible). Also: codebook-phase register prefetch in the
// quant sweep (T14) and B-tile register prefetch in enc1.
//
// Decoder collapse unchanged (validated R7, absmax 0): H2w=cb@dec_w1+b1d,
// BN2 from cnt-weighted stats, Dw=relu(bn2(H2w))@dec_w2+b2d,
// sum((X_-X)^2) = sum_k cnt_k||Dw_k||^2 - 2 sum_n Dw[topic_n].X[n] + sum||X||^2.
// z-path unchanged: h1 fp32, split-bf16 MFMA z, exact fp32 selected-distance.
//
// acc: [0..127] BN1 sum (k_stats), [128..255] BN1 sumsq (k_stats),
//      [256..383] BN2 wsum (code1 atomics), [384..511] BN2 wsumsq,
//      [515] sum||X||^2 (k_stats)

typedef __attribute__((ext_vector_type(8))) short bf8;
typedef __attribute__((ext_vector_type(4))) float f4a;

__device__ __forceinline__ unsigned short f2bf(float f) {
    unsigned u = __float_as_uint(f);
    u += 0x7fffu + ((u >> 16) & 1u);   // RNE
    return (unsigned short)(u >> 16);
}
__device__ __forceinline__ float bf2f(unsigned short h) {
    return __uint_as_float((unsigned)h << 16);
}
__device__ __forceinline__ unsigned pack2(float a, float b) {
    return (unsigned)f2bf(a) | ((unsigned)f2bf(b) << 16);
}

// ======== K0: zero acc/cnt + codebook->bf16+norms + weight prep ========
__global__ __launch_bounds__(256) void k_prep(const float* __restrict__ cb,
                                              const float* __restrict__ w1,
                                              const float* __restrict__ w2e,
                                              float* __restrict__ acc,
                                              int* __restrict__ cnt,
                                              unsigned short* __restrict__ cbb,
                                              float* __restrict__ cn_g,
                                              unsigned short* __restrict__ w1T,
                                              unsigned short* __restrict__ w2eh,
                                              unsigned short* __restrict__ w2el) {
    const int b = blockIdx.x, t = threadIdx.x;
    if (b < 4) {                       // codebook -> bf16 + fp32 norms
        const int cw = (b << 8) + t;
        const float* p = cb + (size_t)cw * 32;
        unsigned out[16];
        float n = 0.f;
#pragma unroll
        for (int i = 0; i < 8; ++i) {
            float4 v = *(const float4*)(p + (i << 2));
            n = fmaf(v.x, v.x, n); n = fmaf(v.y, v.y, n);
            n = fmaf(v.z, v.z, n); n = fmaf(v.w, v.w, n);
            out[2 * i]     = pack2(v.x, v.y);
            out[2 * i + 1] = pack2(v.z, v.w);
        }
#pragma unroll
        for (int i = 0; i < 4; ++i)
            *(uint4*)(cbb + (size_t)cw * 32 + (i << 3)) =
                make_uint4(out[4 * i], out[4 * i + 1], out[4 * i + 2], out[4 * i + 3]);
        cn_g[cw] = n;
    } else if (b == 4) {               // zero accumulators (code1 atomics need it)
        for (int i = t; i < 1024; i += 256) { acc[i] = 0.f; cnt[i] = 0; }
    } else if (b < 21) {               // w1T[n][k] <- bf16(w1[k][n])
        const int n0 = (b - 5) << 3;
        for (int rr = 0; rr < 8; ++rr) {
            const int n = n0 + rr;
            w1T[(size_t)n * 512 + t]       = f2bf(w1[(size_t)t * 128 + n]);
            w1T[(size_t)n * 512 + 256 + t] = f2bf(w1[(size_t)(256 + t) * 128 + n]);
        }
    } else {                           // b==21: w2e hi/lo split [32 n][128 k]
        for (int i = 0; i < 16; ++i) {
            const int idx = (i << 8) + t;
            const int n = idx >> 7, k = idx & 127;
            const float f = w2e[(size_t)k * 32 + n];
            unsigned short hi = f2bf(f);
            w2eh[idx] = hi;
            w2el[idx] = f2bf(f - bf2f(hi));
        }
    }
}

// ======== K1: h1 = fp32(X@w1 + b1); PLAIN per-block stat stores ========
// 512 blocks x 256 thr, 128 rows/block; A+B register prefetch of chunk c+1.
__global__ __launch_bounds__(256, 3) void k_enc1(const float* __restrict__ X,
                                                 const unsigned short* __restrict__ w1T,
                                                 const float* __restrict__ b1,
                                                 float* __restrict__ h1,
                                                 float* __restrict__ colstat,
                                                 float* __restrict__ s2part) {
    __shared__ unsigned short As[128 * 72];
    __shared__ unsigned short Bs[128 * 72];
    __shared__ float sred[1024];
    __shared__ float s2red[4];
    const int t = threadIdx.x;
    const int w = t >> 6, lane = t & 63, quad = lane >> 4, lcol = lane & 15;
    const int row0 = blockIdx.x << 7;

    f4a acc[2][8];
#pragma unroll
    for (int i = 0; i < 2; ++i)
#pragma unroll
        for (int j = 0; j < 8; ++j) acc[i][j] = (f4a){0.f, 0.f, 0.f, 0.f};

    const int arb = t >> 4;               // A: 16 rows per i-step
    const int akq = (t & 15) << 2;        // A k-quad
    const int bnr = t >> 3, bks = (t & 7) << 3;   // B: row / 8-halfword slot

    float4 xa[8];
    uint4 wb[4];
    float s2 = 0.f;
#pragma unroll
    for (int i = 0; i < 8; ++i)
        xa[i] = *(const float4*)(X + (size_t)(row0 + (i << 4) + arb) * 512 + akq);
#pragma unroll
    for (int i = 0; i < 4; ++i)
        wb[i] = *(const uint4*)(w1T + (size_t)((i << 5) + bnr) * 512 + bks);

    for (int c = 0; c < 8; ++c) {
        __syncthreads();
#pragma unroll
        for (int i = 0; i < 8; ++i) {     // A regs -> bf16 LDS (+ ||X||^2)
            const float4 v = xa[i];
            s2 = fmaf(v.x, v.x, s2); s2 = fmaf(v.y, v.y, s2);
            s2 = fmaf(v.z, v.z, s2); s2 = fmaf(v.w, v.w, s2);
            *(uint2*)&As[((i << 4) + arb) * 72 + akq] =
                make_uint2(pack2(v.x, v.y), pack2(v.z, v.w));
        }
#pragma unroll
        for (int i = 0; i < 4; ++i)       // B regs -> LDS
            *(uint4*)&Bs[((i << 5) + bnr) * 72 + bks] = wb[i];
        __syncthreads();
        if (c < 7) {                      // prefetch chunk c+1 before MFMA
            const int k0n = (c + 1) << 6;
#pragma unroll
            for (int i = 0; i < 8; ++i)
                xa[i] = *(const float4*)(X + (size_t)(row0 + (i << 4) + arb) * 512 + k0n + akq);
#pragma unroll
            for (int i = 0; i < 4; ++i)
                wb[i] = *(const uint4*)(w1T + (size_t)((i << 5) + bnr) * 512 + k0n + bks);
        }
#pragma unroll
        for (int ks = 0; ks < 2; ++ks) {
            const bf8 a0 = *(const bf8*)&As[(w * 32 + lcol) * 72 + (ks << 5) + (quad << 3)];
            const bf8 a1 = *(const bf8*)&As[(w * 32 + 16 + lcol) * 72 + (ks << 5) + (quad << 3)];
#pragma unroll
            for (int nt = 0; nt < 8; ++nt) {
                const bf8 bb = *(const bf8*)&Bs[(nt * 16 + lcol) * 72 + (ks << 5) + (quad << 3)];
                acc[0][nt] = __builtin_amdgcn_mfma_f32_16x16x32_bf16(a0, bb, acc[0][nt], 0, 0, 0);
                acc[1][nt] = __builtin_amdgcn_mfma_f32_16x16x32_bf16(a1, bb, acc[1][nt], 0, 0, 0);
            }
        }
    }
    // epilogue: h1 fp32 store + BN1 column stats (block-local, plain stores)
#pragma unroll
    for (int nt = 0; nt < 8; ++nt) {
        const int gc = (nt << 4) + lcol;
        const float bias = b1[gc];
        float s = 0.f, ss = 0.f;
#pragma unroll
        for (int mt = 0; mt < 2; ++mt) {
            const int rbase = row0 + w * 32 + mt * 16 + (quad << 2);
#pragma unroll
            for (int r = 0; r < 4; ++r) {
                float v = acc[mt][nt][r] + bias;
                h1[(size_t)(rbase + r) * 128 + gc] = v;
                s += v;
                ss = fmaf(v, v, ss);
            }
        }
        s += __shfl_xor(s, 16);  s += __shfl_xor(s, 32);
        ss += __shfl_xor(ss, 16); ss += __shfl_xor(ss, 32);
        if (quad == 0) { sred[w * 128 + gc] = s; sred[512 + w * 128 + gc] = ss; }
    }
    s2 += __shfl_xor(s2, 1);  s2 += __shfl_xor(s2, 2);  s2 += __shfl_xor(s2, 4);
    s2 += __shfl_xor(s2, 8);  s2 += __shfl_xor(s2, 16); s2 += __shfl_xor(s2, 32);
    if (lane == 0) s2red[w] = s2;
    __syncthreads();
    if (t < 128) {
        colstat[(size_t)blockIdx.x * 256 + t] =
            sred[t] + sred[128 + t] + sred[256 + t] + sred[384 + t];
        colstat[(size_t)blockIdx.x * 256 + 128 + t] =
            sred[512 + t] + sred[640 + t] + sred[768 + t] + sred[896 + t];
    }
    if (t == 0) s2part[blockIdx.x] = s2red[0] + s2red[1] + s2red[2] + s2red[3];
}

// ======== K1b: sum per-block stats -> acc (plain stores, zero atomics) ========
__global__ __launch_bounds__(256) void k_stats(const float* __restrict__ colstat,
                                               const float* __restrict__ s2part,
                                               float* __restrict__ acc) {
    __shared__ float red[256];
    const int t = threadIdx.x;
    float s = 0.f;
    for (int b = 0; b < 512; ++b) s += colstat[(size_t)b * 256 + t];
    acc[t] = s;
    red[t] = s2part[t] + s2part[256 + t];
    __syncthreads();
    for (int st = 128; st > 0; st >>= 1) {
        if (t < st) red[t] += red[t + st];
        __syncthreads();
    }
    if (t == 0) acc[515] = red[0];
}

// ======== K2: BN1 -> z (split-bf16) -> quantize. PLAIN outputs only. ========
// 1024 blocks x 256 thr, 64 rows/block. Codebook-phase register prefetch;
// LDS histogram -> plain histp row; z_loss partial -> zpart[bid].
__global__ __launch_bounds__(256, 4) void k_quant(const float* __restrict__ h1,
                                                  const float* __restrict__ g1,
                                                  const float* __restrict__ be1,
                                                  const float* __restrict__ b2e,
                                                  const float* __restrict__ cb,
                                                  const unsigned short* __restrict__ cbb,
                                                  const float* __restrict__ cn_g,
                                                  const unsigned short* __restrict__ w2eh,
                                                  const unsigned short* __restrict__ w2el,
                                                  int* __restrict__ topics_g,
                                                  int* __restrict__ histp,
                                                  float* __restrict__ zpart,
                                                  const float* __restrict__ acc_g) {
    __shared__ __align__(16) char pool[35072];
    unsigned short* Ash = (unsigned short*)pool;
    unsigned short* Asl = (unsigned short*)(pool + 9216);
    unsigned short* B2h = (unsigned short*)(pool + 18432);
    unsigned short* B2l = (unsigned short*)(pool + 23040);
    unsigned short* cs  = (unsigned short*)pool;
    float*          cn  = (float*)(pool + 20480);
    int*            hist = (int*)pool;            // overlay cs post-sweep (4KB)
    unsigned short* zs  = (unsigned short*)(pool + 27648);
    float* scl = (float*)(pool + 32768);
    float* shf = (float*)(pool + 33280);
    float* red = (float*)(pool + 34048);

    const int t = threadIdx.x;
    const int w = t >> 6, lane = t & 63, quad = lane >> 4, lcol = lane & 15;
    const int row0 = blockIdx.x << 6;

    if (t < 128) {   // BN1 params (acc written plain by k_stats)
        float mu = acc_g[t] * (1.f / 65536.f);
        float var = fmaf(-mu, mu, acc_g[128 + t] * (1.f / 65536.f));
        float s = g1[t] * rsqrtf(var + 1e-5f);
        scl[t] = s;
        shf[t] = fmaf(-mu, s, be1[t]);
    }
    __syncthreads();

    f4a zacc[2];
#pragma unroll
    for (int j = 0; j < 2; ++j) zacc[j] = (f4a){0.f, 0.f, 0.f, 0.f};

    const int rb = t >> 4;
    const int kq = (t & 15) << 2;
#pragma unroll
    for (int h = 0; h < 2; ++h) {
        const int gk = (h << 6) + kq;
        const float4 sc = *(const float4*)&scl[gk];
        const float4 sh = *(const float4*)&shf[gk];
#pragma unroll
        for (int i = 0; i < 4; ++i) {
            const int r = (i << 4) + rb;
            float4 v = *(const float4*)(h1 + (size_t)(row0 + r) * 128 + gk);
            float a0 = fmaxf(fmaf(v.x, sc.x, sh.x), 0.f);
            float a1 = fmaxf(fmaf(v.y, sc.y, sh.y), 0.f);
            float a2 = fmaxf(fmaf(v.z, sc.z, sh.z), 0.f);
            float a3 = fmaxf(fmaf(v.w, sc.w, sh.w), 0.f);
            unsigned short h0 = f2bf(a0), h1u = f2bf(a1), h2u = f2bf(a2), h3 = f2bf(a3);
            *(uint2*)&Ash[r * 72 + kq] = make_uint2(
                (unsigned)h0 | ((unsigned)h1u << 16), (unsigned)h2u | ((unsigned)h3 << 16));
            *(uint2*)&Asl[r * 72 + kq] = make_uint2(
                (unsigned)f2bf(a0 - bf2f(h0)) | ((unsigned)f2bf(a1 - bf2f(h1u)) << 16),
                (unsigned)f2bf(a2 - bf2f(h2u)) | ((unsigned)f2bf(a3 - bf2f(h3)) << 16));
        }
        *(uint4*)&B2h[(t >> 3) * 72 + ((t & 7) << 3)] =
            *(const uint4*)(w2eh + (size_t)(t >> 3) * 128 + (h << 6) + ((t & 7) << 3));
        *(uint4*)&B2l[(t >> 3) * 72 + ((t & 7) << 3)] =
            *(const uint4*)(w2el + (size_t)(t >> 3) * 128 + (h << 6) + ((t & 7) << 3));
        __syncthreads();
#pragma unroll
        for (int kc = 0; kc < 2; ++kc) {
            const int ko = (kc << 5) + (quad << 3);
            const bf8 ah = *(const bf8*)&Ash[(w * 16 + lcol) * 72 + ko];
            const bf8 al = *(const bf8*)&Asl[(w * 16 + lcol) * 72 + ko];
            const bf8 bh0 = *(const bf8*)&B2h[lcol * 72 + ko];
            const bf8 bh1 = *(const bf8*)&B2h[(16 + lcol) * 72 + ko];
            const bf8 bl0 = *(const bf8*)&B2l[lcol * 72 + ko];
            const bf8 bl1 = *(const bf8*)&B2l[(16 + lcol) * 72 + ko];
            zacc[0] = __builtin_amdgcn_mfma_f32_16x16x32_bf16(ah, bh0, zacc[0], 0, 0, 0);
            zacc[0] = __builtin_amdgcn_mfma_f32_16x16x32_bf16(al, bh0, zacc[0], 0, 0, 0);
            zacc[0] = __builtin_amdgcn_mfma_f32_16x16x32_bf16(ah, bl0, zacc[0], 0, 0, 0);
            zacc[1] = __builtin_amdgcn_mfma_f32_16x16x32_bf16(ah, bh1, zacc[1], 0, 0, 0);
            zacc[1] = __builtin_amdgcn_mfma_f32_16x16x32_bf16(al, bh1, zacc[1], 0, 0, 0);
            zacc[1] = __builtin_amdgcn_mfma_f32_16x16x32_bf16(ah, bl1, zacc[1], 0, 0, 0);
        }
        __syncthreads();
    }
    const float b2lo = b2e[lcol], b2hi = b2e[16 + lcol];
    float zf0[4], zf1[4];
#pragma unroll
    for (int r = 0; r < 4; ++r) {
        float v0 = zacc[0][r] + b2lo;
        float v1 = zacc[1][r] + b2hi;
        zf0[r] = v0;
        zf1[r] = v1;
        int row = w * 16 + (quad << 2) + r;
        zs[row * 40 + lcol] = f2bf(v0);
        zs[row * 40 + 16 + lcol] = f2bf(v1);
    }
    __syncthreads();

    // --- quant sweep with codebook-phase register prefetch ---
    const bf8 af = *(const bf8*)&zs[(w * 16 + lcol) * 40 + (quad << 3)];
    float best[4];
    int bidx[4];
#pragma unroll
    for (int r = 0; r < 4; ++r) { best[r] = 3.4e38f; bidx[r] = 0; }
    const f4a zero4 = {0.f, 0.f, 0.f, 0.f};

    // stage cp=0
#pragma unroll
    for (int i = 0; i < 4; ++i) {
        int idx = (i << 8) + t;
        int r = idx >> 2, kq2 = (idx & 3) << 3;
        *(uint4*)&cs[r * 40 + kq2] = *(const uint4*)(cbb + (size_t)r * 32 + kq2);
    }
    cn[t] = cn_g[t];
    __syncthreads();
    for (int cp = 0; cp < 4; ++cp) {
        uint4 pf[4];
        float pfcn = 0.f;
        if (cp < 3) {   // issue cp+1 loads before the sweep (latency hidden)
#pragma unroll
            for (int i = 0; i < 4; ++i) {
                int idx = (i << 8) + t;
                int r = idx >> 2, kq2 = (idx & 3) << 3;
                pf[i] = *(const uint4*)(cbb + (size_t)(((cp + 1) << 8) + r) * 32 + kq2);
            }
            pfcn = cn_g[((cp + 1) << 8) + t];
        }
        bf8 bb = *(const bf8*)&cs[lcol * 40 + (quad << 3)];
        float cnv = cn[lcol];
        for (int ch = 0; ch < 16; ++ch) {
            const int nn = ((ch + 1) & 15) << 4;
            const bf8 bb_n = *(const bf8*)&cs[(nn + lcol) * 40 + (quad << 3)];
            const float cn_n = cn[nn + lcol];
            const int cidx = (cp << 8) + (ch << 4) + lcol;
            f4a a = __builtin_amdgcn_mfma_f32_16x16x32_bf16(af, bb, zero4, 0, 0, 0);
#pragma unroll
            for (int r = 0; r < 4; ++r) {
                float d = fmaf(-2.f, a[r], cnv);
                if (d < best[r]) { best[r] = d; bidx[r] = cidx; }
            }
            bb = bb_n; cnv = cn_n;
        }
        __syncthreads();   // all cs/cn reads of this phase done
        if (cp < 3) {
#pragma unroll
            for (int i = 0; i < 4; ++i) {
                int idx = (i << 8) + t;
                int r = idx >> 2, kq2 = (idx & 3) << 3;
                *(uint4*)&cs[r * 40 + kq2] = pf[i];
            }
            cn[t] = pfcn;
            __syncthreads();
        }
    }
    // cs region dead -> LDS histogram
#pragma unroll
    for (int i = 0; i < 4; ++i) hist[(i << 8) + t] = 0;
    __syncthreads();
    // cross-lane argmin (register-only)
#pragma unroll
    for (int off = 1; off < 16; off <<= 1) {
#pragma unroll
        for (int r = 0; r < 4; ++r) {
            float ob = __shfl_xor(best[r], off);
            int oi = __shfl_xor(bidx[r], off);
            if (ob < best[r] || (ob == best[r] && oi < bidx[r])) {
                best[r] = ob; bidx[r] = oi;
            }
        }
    }
    // exact fp32 distance + topics + LDS-histogram
    float lsum = 0.f;
#pragma unroll
    for (int r = 0; r < 4; ++r) {
        const int rowl = w * 16 + (quad << 2) + r;
        const int ti = bidx[r];
        const float* cp_ = cb + (size_t)ti * 32;
        float d0 = zf0[r] - cp_[lcol];
        float d1 = zf1[r] - cp_[16 + lcol];
        float p = fmaf(d0, d0, d1 * d1);
        p += __shfl_xor(p, 1); p += __shfl_xor(p, 2);
        p += __shfl_xor(p, 4); p += __shfl_xor(p, 8);
        if (lcol == 0) {
            topics_g[row0 + rowl] = ti;
            atomicAdd(&hist[ti], 1);   // LDS atomic (fast, per-CU)
            lsum += p;
        }
    }
    red[t] = lsum;
    __syncthreads();
    for (int s = 128; s > 0; s >>= 1) {
        if (t < s) red[t] += red[t + s];
        __syncthreads();
    }
    if (t == 0) zpart[blockIdx.x] = red[0];   // plain store, no atomic
    // flush histogram row (plain coalesced stores)
#pragma unroll
    for (int i = 0; i < 4; ++i)
        histp[(size_t)blockIdx.x * 1024 + (i << 8) + t] = hist[(i << 8) + t];
}

// ======== K2b: cnt[k] = sum_b histp[b][k] (plain, zero atomics) ========
__global__ __launch_bounds__(256) void k_hist(const int* __restrict__ histp,
                                              int* __restrict__ cnt) {
    const int k = blockIdx.x * 256 + threadIdx.x;
    int s = 0;
    for (int b = 0; b < 1024; ++b) s += histp[(size_t)b * 1024 + k];
    cnt[k] = s;
}

// ======== K3a: H2w = cb@dec_w1 + b1d + cnt-weighted BN2 sums (8 blocks) ========
__global__ __launch_bounds__(256) void k_code1(const float* __restrict__ cb,
                                               const float* __restrict__ w1d,
                                               const float* __restrict__ b1d,
                                               const int* __restrict__ cnt,
                                               float* __restrict__ H2w,
                                               float* __restrict__ acc_g) {
    __shared__ float cbs[128 * 32];   // 16KB: this block's codeword rows
    const int t = threadIdx.x;
    const int k0 = blockIdx.x << 7;
#pragma unroll
    for (int i = 0; i < 16; ++i) {
        const int idx = (i << 8) + t;
        cbs[idx] = cb[(size_t)k0 * 32 + idx];
    }
    const int c = t & 127, half = t >> 7;
    float w1v[32];
#pragma unroll
    for (int j = 0; j < 32; ++j) w1v[j] = w1d[(size_t)j * 128 + c];
    __syncthreads();
    const float bias = b1d[c];
    float ps = 0.f, pss = 0.f;
    for (int kk = 0; kk < 64; ++kk) {
        const int kl = (half << 6) + kk;
        const float* cr = &cbs[kl << 5];
        float a = bias;
#pragma unroll
        for (int j = 0; j < 32; ++j) a = fmaf(cr[j], w1v[j], a);
        H2w[(size_t)(k0 + kl) * 128 + c] = a;
        const float cf = (float)cnt[k0 + kl];
        ps = fmaf(cf, a, ps);
        pss = fmaf(cf * a, a, pss);
    }
    atomicAdd(&acc_g[256 + c], ps);    // 16 atomics/address total — negligible
    atomicAdd(&acc_g[384 + c], pss);
}

// ======== K3b: Dw = relu(bn2(H2w))@dec_w2 + b2d + cnt||Dw||^2 partial ========
__global__ __launch_bounds__(256) void k_code2(const float* __restrict__ H2w,
                                               const float* __restrict__ w2d,
                                               const float* __restrict__ b2d,
                                               const float* __restrict__ g2,
                                               const float* __restrict__ be2,
                                               const int* __restrict__ cnt,
                                               float* __restrict__ Dw,
                                               float* __restrict__ dpart,
                                               const float* __restrict__ acc_g) {
    __shared__ float Hr[8][128];
    __shared__ float scl[128], shf[128];
    __shared__ float red[256];
    const int t = threadIdx.x;
    const int k0 = blockIdx.x << 3;
    if (t < 128) {
        float mu = acc_g[256 + t] * (1.f / 65536.f);
        float var = fmaf(-mu, mu, acc_g[384 + t] * (1.f / 65536.f));
        float s = g2[t] * rsqrtf(var + 1e-5f);
        scl[t] = s;
        shf[t] = fmaf(-mu, s, be2[t]);
    }
    __syncthreads();
#pragma unroll
    for (int i = 0; i < 4; ++i) {
        const int idx = (i << 8) + t;
        const int kk = idx >> 7, j = idx & 127;
        const float v = H2w[(size_t)(k0 + kk) * 128 + j];
        Hr[kk][j] = fmaxf(fmaf(v, scl[j], shf[j]), 0.f);
    }
    __syncthreads();
    float a0[8], a1[8];
#pragma unroll
    for (int kk = 0; kk < 8; ++kk) { a0[kk] = 0.f; a1[kk] = 0.f; }
#pragma unroll 4
    for (int j = 0; j < 128; ++j) {
        const float w0 = w2d[(size_t)j * 512 + t];
        const float w1v = w2d[(size_t)j * 512 + 256 + t];
#pragma unroll
        for (int kk = 0; kk < 8; ++kk) {
            const float h = Hr[kk][j];
            a0[kk] = fmaf(h, w0, a0[kk]);
            a1[kk] = fmaf(h, w1v, a1[kk]);
        }
    }
    const float bb0 = b2d[t], bb1 = b2d[256 + t];
    float pd = 0.f;
#pragma unroll
    for (int kk = 0; kk < 8; ++kk) {
        const float cf = (float)cnt[k0 + kk];
        const float v0 = a0[kk] + bb0;
        const float v1 = a1[kk] + bb1;
        Dw[(size_t)(k0 + kk) * 512 + t] = v0;
        Dw[(size_t)(k0 + kk) * 512 + 256 + t] = v1;
        pd += cf * fmaf(v0, v0, v1 * v1);
    }
    red[t] = pd;
    __syncthreads();
    for (int s = 128; s > 0; s >>= 1) {
        if (t < s) red[t] += red[t + s];
        __syncthreads();
    }
    if (t == 0) dpart[blockIdx.x] = red[0];   // plain store
}

// ======== K4: cross partials = sum_n Dw[topic_n].X[n], per-block plain store ========
__global__ __launch_bounds__(256, 8) void k_cross(const float* __restrict__ X,
                                                  const float* __restrict__ Dw,
                                                  const int* __restrict__ topics_g,
                                                  float* __restrict__ crosspart) {
    __shared__ float cred[4];
    const int t = threadIdx.x;
    const int w = t >> 6, lane = t & 63;
    const int row0 = (blockIdx.x << 6) + (w << 4);
    float cr = 0.f;
#pragma unroll 4
    for (int i = 0; i < 16; ++i) {
        const int row = row0 + i;
        const int tp = topics_g[row];
        const float* xp = X + (size_t)row * 512 + (lane << 3);
        const float* dp = Dw + (size_t)tp * 512 + (lane << 3);
        float4 x0 = *(const float4*)xp;
        float4 x1 = *(const float4*)(xp + 4);
        float4 d0 = *(const float4*)dp;
        float4 d1 = *(const float4*)(dp + 4);
        cr = fmaf(x0.x, d0.x, cr); cr = fmaf(x0.y, d0.y, cr);
        cr = fmaf(x0.z, d0.z, cr); cr = fmaf(x0.w, d0.w, cr);
        cr = fmaf(x1.x, d1.x, cr); cr = fmaf(x1.y, d1.y, cr);
        cr = fmaf(x1.z, d1.z, cr); cr = fmaf(x1.w, d1.w, cr);
    }
    cr += __shfl_xor(cr, 1);  cr += __shfl_xor(cr, 2);  cr += __shfl_xor(cr, 4);
    cr += __shfl_xor(cr, 8);  cr += __shfl_xor(cr, 16); cr += __shfl_xor(cr, 32);
    if (lane == 0) cred[w] = cr;
    __syncthreads();
    if (t == 0) crosspart[blockIdx.x] = cred[0] + cred[1] + cred[2] + cred[3];
}

// ======== K5: final reduction of all partials ========
__global__ __launch_bounds__(256) void k_final(const float* __restrict__ acc,
                                               const float* __restrict__ zpart,
                                               const float* __restrict__ dpart,
                                               const float* __restrict__ crosspart,
                                               float* __restrict__ out) {
    __shared__ float red[256];
    const int t = threadIdx.x;
    float z = zpart[t] + zpart[256 + t] + zpart[512 + t] + zpart[768 + t];
    float d = (t < 128) ? dpart[t] : 0.f;
    float c = crosspart[t] + crosspart[256 + t] + crosspart[512 + t] + crosspart[768 + t];
    red[t] = z;
    __syncthreads();
    for (int s = 128; s > 0; s >>= 1) {
        if (t < s) red[t] += red[t + s];
        __syncthreads();
    }
    float zsum = red[0];
    __syncthreads();
    red[t] = d;
    __syncthreads();
    for (int s = 128; s > 0; s >>= 1) {
        if (t < s) red[t] += red[t + s];
        __syncthreads();
    }
    float dsum = red[0];
    __syncthreads();
    red[t] = c;
    __syncthreads();
    for (int s = 128; s > 0; s >>= 1) {
        if (t < s) red[t] += red[t + s];
        __syncthreads();
    }
    if (t == 0)
        out[0] = 2.f * zsum + sqrtf(dsum - 2.f * red[0] + acc[515]);
}

extern "C" void kernel_launch(void* const* d_in, const int* in_sizes, int n_in,
                              void* d_out, int out_size, void* d_ws, size_t ws_size,
                              hipStream_t stream) {
    const float* X       = (const float*)d_in[0];
    const float* enc_w1  = (const float*)d_in[1];
    const float* enc_b1  = (const float*)d_in[2];
    const float* enc_g1  = (const float*)d_in[3];
    const float* enc_be1 = (const float*)d_in[4];
    const float* enc_w2  = (const float*)d_in[5];
    const float* enc_b2  = (const float*)d_in[6];
    const float* dec_w1  = (const float*)d_in[7];
    const float* dec_b1  = (const float*)d_in[8];
    const float* dec_g1  = (const float*)d_in[9];
    const float* dec_be1 = (const float*)d_in[10];
    const float* dec_w2  = (const float*)d_in[11];
    const float* dec_b2  = (const float*)d_in[12];
    const float* cb      = (const float*)d_in[13];
    float* out = (float*)d_out;

    float* acc = (float*)d_ws;                                // 1024 f32
    int* cnt = (int*)(acc + 1024);                            // 1024 i32
    unsigned short* cbb = (unsigned short*)(cnt + 1024);      // 1024*32 bf16
    float* cn_g = (float*)(cbb + 32768);                      // 1024 f32
    unsigned short* w1T  = (unsigned short*)(cn_g + 1024);    // [128][512] bf16
    unsigned short* w2eh = w1T + 65536;                       // [32][128] bf16
    unsigned short* w2el = w2eh + 4096;                       // [32][128] bf16
    int* topics = (int*)(w2el + 4096);                        // 65536 i32
    float* colstat = (float*)(topics + 65536);                // [512][256] f32
    float* s2part = colstat + 512 * 256;                      // 512 f32
    float* zpart = s2part + 512;                              // 1024 f32
    float* dpart = zpart + 1024;                              // 128 f32
    float* crosspart = dpart + 128;                           // 1024 f32
    int* histp = (int*)(crosspart + 1024);                    // [1024][1024] i32
    float* h1 = (float*)(histp + (size_t)1024 * 1024);        // [65536][128] f32
    float* H2w = h1 + (size_t)65536 * 128;                    // [1024][128] f32
    float* Dw = H2w + 1024 * 128;                             // [1024][512] f32

    k_prep<<<22, 256, 0, stream>>>(cb, enc_w1, enc_w2, acc, cnt, cbb, cn_g,
                                   w1T, w2eh, w2el);
    k_enc1<<<512, 256, 0, stream>>>(X, w1T, enc_b1, h1, colstat, s2part);
    k_stats<<<1, 256, 0, stream>>>(colstat, s2part, acc);
    k_quant<<<1024, 256, 0, stream>>>(h1, enc_g1, enc_be1, enc_b2, cb, cbb, cn_g,
                                      w2eh, w2el, topics, histp, zpart, acc);
    k_hist<<<4, 256, 0, stream>>>(histp, cnt);
    k_code1<<<8, 256, 0, stream>>>(cb, dec_w1, dec_b1, cnt, H2w, acc);
    k_code2<<<128, 256, 0, stream>>>(H2w, dec_w2, dec_b2, dec_g1, dec_be1, cnt,
                                     Dw, dpart, acc);
    k_cross<<<1024, 256, 0, stream>>>(X, Dw, topics, crosspart);
    k_final<<<1, 256, 0, stream>>>(acc, zpart, dpart, crosspart, out);
}